// Round 1
// 1310.696 us; speedup vs baseline: 1.0692x; 1.0692x over previous
//
#include <hip/hip_runtime.h>
#include <hip/hip_bf16.h>

#define T_STEPS 4
#define N 4096
#define E 65536
#define XD 256
#define HD 256
#define ZD 64

typedef __hip_bfloat16 bf16;
typedef __attribute__((ext_vector_type(8))) short short8;
typedef __attribute__((ext_vector_type(4))) float f32x4;

__device__ __forceinline__ float b2f(bf16 v){ return __bfloat162float(v); }
__device__ __forceinline__ bf16 f2b(float v){ return __float2bfloat16(v); }
__device__ __forceinline__ short f2s(float v){ return __builtin_bit_cast(short, f2b(v)); }
__device__ __forceinline__ float bits2f(unsigned int s){ return __builtin_bit_cast(float, s << 16); }
__device__ __forceinline__ float s2f(short s){ return bits2f((unsigned int)(unsigned short)s); }
// fast transcendentals (HW exp2/log2 based; ~1e-6 rel err — far under the 6e-2 threshold)
__device__ __forceinline__ float splus(float x){ return (x > 15.f) ? x : __logf(1.f + __expf(x)); }
__device__ __forceinline__ float sigm(float x){ return 1.f/(1.f + __expf(-x)); }
__device__ __forceinline__ float ftanh(float x){ return 2.f/(1.f + __expf(-2.f*x)) - 1.f; }

__device__ __forceinline__ float ldI(const void* p, size_t i, int f){
  return f ? ((const float*)p)[i] : b2f(((const bf16*)p)[i]);
}
__device__ __forceinline__ void stO(void* p, size_t i, float v, int f){
  if (f) ((float*)p)[i] = v; else ((bf16*)p)[i] = f2b(v);
}
__device__ __forceinline__ void ld8b(const bf16* p, float v[8]){
  uint4 u = *(const uint4*)p;
  v[0]=bits2f(u.x & 0xffffu); v[1]=bits2f(u.x >> 16);
  v[2]=bits2f(u.y & 0xffffu); v[3]=bits2f(u.y >> 16);
  v[4]=bits2f(u.z & 0xffffu); v[5]=bits2f(u.z >> 16);
  v[6]=bits2f(u.w & 0xffffu); v[7]=bits2f(u.w >> 16);
}
__device__ __forceinline__ void ldW8(const void* W, size_t off, int f, float w[8]){
  if (f == 0){ ld8b((const bf16*)W + off, w); }
  else {
    const float* Wf = (const float*)W + off;
    float4 a = *(const float4*)Wf, b = *(const float4*)(Wf + 4);
    w[0]=a.x; w[1]=a.y; w[2]=a.z; w[3]=a.w; w[4]=b.x; w[5]=b.y; w[6]=b.z; w[7]=b.w;
  }
}
__device__ __forceinline__ unsigned int pack2(float a, float b){
  return (unsigned int)(unsigned short)__builtin_bit_cast(unsigned short, f2b(a))
       | ((unsigned int)(unsigned short)__builtin_bit_cast(unsigned short, f2b(b)) << 16);
}
__device__ __forceinline__ uint4 pack8(const float v[8]){
  uint4 o; o.x = pack2(v[0],v[1]); o.y = pack2(v[2],v[3]);
  o.z = pack2(v[4],v[5]); o.w = pack2(v[6],v[7]);
  return o;
}
__device__ __forceinline__ unsigned int pack2s(short a, short b){
  return (unsigned int)(unsigned short)a | ((unsigned int)(unsigned short)b << 16);
}
__device__ __forceinline__ const void* wofs(const void* W, int f, size_t elems){
  return f ? (const void*)((const float*)W + elems) : (const void*)((const bf16*)W + elems);
}

// per-kernel shared structs (split so pure-GEMM kernels allocate only 18.4 KB)
struct GemmSM { short As[64*72]; short Wt[64*72]; };                     // 18.4 KB
struct DecSM  { short Zi[64*72]; short Zj[64*72]; short Adj[64*72];
                float redA[256]; float redB[256]; float redC[256]; };    // 30.7 KB
struct EncSM  { short At[16*264]; short Wt[128*40]; };                   // 18.7 KB

struct KP {
  const void *x, *adj, *eps, *h0;
  const int* ei;
  const void *phi_x_w, *phi_x_b, *phi_z_w, *phi_z_b;
  const void *enc_w, *enc_b, *enc_mean_w, *enc_mean_b, *enc_std_w, *enc_std_b;
  const void *prior_w, *prior_b, *prior_mean_w, *prior_mean_b, *prior_std_w, *prior_std_b;
  const void *gxz, *ghz, *gxr, *ghr, *gxh, *ghh;
  void* out;
  float* scal; int* dflag; float* dinv; int* offs; int* srcs; float* enorm; int* deg;
  float* h_prev; bf16* h_bf; bf16* phiXa; bf16* Tb1; bf16* Tb2;
  bf16* zbf; float* z_g; bf16* Gs1; bf16* Gsx; bf16* Gms; bf16* Gh2;
  bf16* PreB;     // T x N x 1024 precomputed phiX @ [enc_top | gxz_top | gxr_top | gxh_top]
};

#define OUT_EM ((size_t)2)
#define OUT_PM ((size_t)(2 + (size_t)T_STEPS*N*ZD))
#define OUT_H  ((size_t)(2 + (size_t)2*T_STEPS*N*ZD))

// ---------------- MFMA 64x64 tile: C = A @ W(+bias)(+pre)(+relu), bf16 out ----------------
// K-chunk = 64: half the barriers of the old 32-chunk version; W transpose staged with
// packed ds_write_b32 (adjacent k-pair lands in adjacent shorts under the XOR swizzle).
__device__ void mfma_tile(GemmSM& sm, int tid, int f,
    const void* A, int am, int lda, int K,
    const void* W, int ldw, int wcol,
    const void* bias, int act, bf16* C, int ldc, int row0, int ccol0,
    const bf16* pre, int ldpre){
  int ar = tid >> 2, akk = (tid & 3)*16;          // A: 64 rows x 64 k, 16 elems/thread
  int kp2 = (tid >> 3)*2, wn = (tid & 7)*8;       // W: k rows kp2,kp2+1 (64 k), 8 cols
  int wave = tid >> 6, lane = tid & 63, m = lane & 15, kq = lane >> 4;
  f32x4 acc[4] = {};
  for (int k0 = 0; k0 < K; k0 += 64){
    size_t aidx = (size_t)(row0 + ar)*lda + k0 + akk;
    short8 av0, av1;
    if (am == 2 || f == 0){
      av0 = *(const short8*)((const short*)A + aidx);
      av1 = *(const short8*)((const short*)A + aidx + 8);
    } else {
      const float* Af = (const float*)A + aidx;
      float4 u0 = *(const float4*)(Af);
      float4 u1 = *(const float4*)(Af + 4);
      float4 u2 = *(const float4*)(Af + 8);
      float4 u3 = *(const float4*)(Af + 12);
      av0[0]=f2s(u0.x); av0[1]=f2s(u0.y); av0[2]=f2s(u0.z); av0[3]=f2s(u0.w);
      av0[4]=f2s(u1.x); av0[5]=f2s(u1.y); av0[6]=f2s(u1.z); av0[7]=f2s(u1.w);
      av1[0]=f2s(u2.x); av1[1]=f2s(u2.y); av1[2]=f2s(u2.z); av1[3]=f2s(u2.w);
      av1[4]=f2s(u3.x); av1[5]=f2s(u3.y); av1[6]=f2s(u3.z); av1[7]=f2s(u3.w);
    }
    size_t wi = (size_t)(k0 + kp2)*ldw + wcol + wn;
    short w0[8], w1[8];
    if (f == 0){
      short8 t0 = *(const short8*)((const short*)W + wi);
      short8 t1 = *(const short8*)((const short*)W + wi + ldw);
      #pragma unroll
      for (int j = 0; j < 8; j++){ w0[j] = t0[j]; w1[j] = t1[j]; }
    } else {
      float wf0[8], wf1[8];
      ldW8(W, wi, 1, wf0); ldW8(W, wi + ldw, 1, wf1);
      #pragma unroll
      for (int j = 0; j < 8; j++){ w0[j] = f2s(wf0[j]); w1[j] = f2s(wf1[j]); }
    }
    *(short8*)&sm.As[ar*72 + akk]     = av0;
    *(short8*)&sm.As[ar*72 + akk + 8] = av1;
    #pragma unroll
    for (int j = 0; j < 8; j++){
      int nrow = wn + j;
      int col = (((kp2 >> 3) ^ ((nrow >> 3) & 7)) << 3) | (kp2 & 7);
      *(unsigned int*)&sm.Wt[nrow*72 + col] = pack2s(w0[j], w1[j]);
    }
    __syncthreads();
    short8 afr0 = *(const short8*)&sm.As[(wave*16 + m)*72 + kq*8];
    short8 afr1 = *(const short8*)&sm.As[(wave*16 + m)*72 + (kq + 4)*8];
    #pragma unroll
    for (int t4 = 0; t4 < 4; t4++){
      int nb = t4*16 + m, sb = (nb >> 3) & 7;
      short8 b0 = *(const short8*)&sm.Wt[nb*72 + ((kq ^ sb) << 3)];
      short8 b1 = *(const short8*)&sm.Wt[nb*72 + (((kq + 4) ^ sb) << 3)];
      acc[t4] = __builtin_amdgcn_mfma_f32_16x16x32_bf16(afr0, b0, acc[t4], 0, 0, 0);
      acc[t4] = __builtin_amdgcn_mfma_f32_16x16x32_bf16(afr1, b1, acc[t4], 0, 0, 0);
    }
    __syncthreads();
  }
  #pragma unroll
  for (int t4 = 0; t4 < 4; t4++){
    int c = ccol0 + t4*16 + m;
    float bv = bias ? ldI(bias, wcol + t4*16 + m, f) : 0.f;
    #pragma unroll
    for (int reg = 0; reg < 4; reg++){
      int r = row0 + wave*16 + kq*4 + reg;
      float v = acc[t4][reg] + bv;
      if (pre) v += b2f(pre[(size_t)r*ldpre + t4*16 + m]);
      if (act == 1) v = fmaxf(v, 0.f);
      C[(size_t)r*ldc + c] = f2b(v);
    }
  }
}

// ---------------- dec 64x64 tile via MFMA, adj through LDS, fused 3-way reduce ------------
__device__ void dec_tile1(const KP& p, DecSM& d, int tid, int t, int u, int f){
  int i0 = (u >> 6)*64, j0 = (u & 63)*64;
  size_t aoff = (size_t)t*N*N;
  #pragma unroll
  for (int i = 0; i < 2; i++){
    int idx = tid + i*256;
    int r = idx >> 3, c = idx & 7;
    int col = ((c ^ ((r >> 3) & 3)) << 3);
    *(short8*)&d.Zi[r*72 + col] = *(const short8*)((const short*)p.zbf + (size_t)(i0+r)*ZD + c*8);
    *(short8*)&d.Zj[r*72 + col] = *(const short8*)((const short*)p.zbf + (size_t)(j0+r)*ZD + c*8);
  }
  {
    int row = tid >> 2, c0 = (tid & 3)*16;
    if (f){
      const float* ap = (const float*)p.adj + aoff + (size_t)(i0+row)*N + j0 + c0;
      short tmp[16];
      #pragma unroll
      for (int q = 0; q < 16; q += 4){
        float4 v = *(const float4*)(ap + q);
        tmp[q]=f2s(v.x); tmp[q+1]=f2s(v.y); tmp[q+2]=f2s(v.z); tmp[q+3]=f2s(v.w);
      }
      *(short8*)&d.Adj[row*72 + c0]     = *(short8*)&tmp[0];
      *(short8*)&d.Adj[row*72 + c0 + 8] = *(short8*)&tmp[8];
    } else {
      const short* ap = (const short*)p.adj + aoff + (size_t)(i0+row)*N + j0 + c0;
      *(short8*)&d.Adj[row*72 + c0]     = *(const short8*)ap;
      *(short8*)&d.Adj[row*72 + c0 + 8] = *(const short8*)(ap + 8);
    }
  }
  __syncthreads();
  int wave = tid >> 6, lane = tid & 63, m = lane & 15, kq = lane >> 4;
  int ra = wave*16 + m, sa = (ra >> 3) & 3;
  short8 a1 = *(const short8*)&d.Zi[ra*72 + ((kq ^ sa) << 3)];
  short8 a2 = *(const short8*)&d.Zi[ra*72 + (((kq+4) ^ sa) << 3)];
  f32x4 acc[4] = {};
  #pragma unroll
  for (int t4 = 0; t4 < 4; t4++){
    int rb = t4*16 + m, sb2 = (rb >> 3) & 3;
    short8 b1 = *(const short8*)&d.Zj[rb*72 + ((kq ^ sb2) << 3)];
    short8 b2 = *(const short8*)&d.Zj[rb*72 + (((kq+4) ^ sb2) << 3)];
    acc[t4] = __builtin_amdgcn_mfma_f32_16x16x32_bf16(a1, b1, acc[t4], 0, 0, 0);
    acc[t4] = __builtin_amdgcn_mfma_f32_16x16x32_bf16(a2, b2, acc[t4], 0, 0, 0);
  }
  float lts = 0.f, lP = 0.f, lQ = 0.f;
  #pragma unroll
  for (int t4 = 0; t4 < 4; t4++){
    int lj = t4*16 + m;
    #pragma unroll
    for (int reg = 0; reg < 4; reg++){
      int li = wave*16 + kq*4 + reg;
      float av = s2f(d.Adj[li*72 + lj]);
      float dec = sigm(acc[t4][reg]);
      lts += av;
      lQ += (1.f - av)*splus(dec);
      if (av != 0.f) lP += av*splus(-dec);
    }
  }
  __syncthreads();
  d.redA[tid] = lts; d.redB[tid] = lP; d.redC[tid] = lQ;
  __syncthreads();
  for (int o = 128; o > 0; o >>= 1){
    if (tid < o){
      d.redA[tid] += d.redA[tid+o];
      d.redB[tid] += d.redB[tid+o];
      d.redC[tid] += d.redC[tid+o];
    }
    __syncthreads();
  }
  if (tid == 0){
    atomicAdd(p.scal + 8 + t,  d.redA[0]);
    atomicAdd(p.scal + 12 + t, d.redB[0]);
    atomicAdd(p.scal + 16 + t, d.redC[0]);
  }
}

// ---------------- setup kernels ----------------
__global__ __launch_bounds__(256) void setup0_k(KP p){
  int gb = blockIdx.x, tid = threadIdx.x;
  if (gb == 0){ if (tid < 64) p.scal[tid] = 0.f; }
  else if (gb == 1){
    if (tid == 0){
      const unsigned short* u = (const unsigned short*)p.x;
      int big = 0;
      for (int i = 0; i < 256; i++){ int e = (u[i] >> 7) & 0xFF; if (e >= 134) big++; }
      *p.dflag = (big > 16) ? 1 : 0;
    }
  } else {
    p.deg[(gb-2)*256 + tid] = 0;
  }
}

__global__ __launch_bounds__(256) void count_deg_k(KP p){
  int idx = blockIdx.x*256 + threadIdx.x;
  int t = idx >> 16, e = idx & (E-1);
  int dst = p.ei[(size_t)t*2*E + E + e] & (N-1);
  atomicAdd(&p.deg[t*N + dst], 1);
}

// scan+cursor (0-3) + h0 copy (4-35) + phi_x GEMM (36-1059)
__global__ __launch_bounds__(256) void setup2_k(KP p){
  __shared__ union { int sh[256]; GemmSM g; } sm;
  int gb = blockIdx.x, tid = threadIdx.x;
  int f = *p.dflag;
  if (gb < 4){
    int t = gb;
    const int* dg = p.deg + t*N;
    int* of = p.offs + t*(N+1);
    int base = tid*16;
    int loc[16]; int s = 0;
    #pragma unroll
    for (int i = 0; i < 16; i++){ loc[i] = s; s += dg[base+i]; }
    sm.sh[tid] = s;
    __syncthreads();
    for (int o = 1; o < 256; o <<= 1){
      int v = (tid >= o) ? sm.sh[tid-o] : 0;
      __syncthreads();
      sm.sh[tid] += v;
      __syncthreads();
    }
    int pre = (tid == 0) ? 0 : sm.sh[tid-1];
    #pragma unroll
    for (int i = 0; i < 16; i++){
      int deg_i = dg[base+i];
      of[base+i] = pre + loc[i];
      p.dinv[t*N + base + i] = rsqrtf(1.f + (float)deg_i);
    }
    if (tid == 255) of[N] = sm.sh[255];
    __syncthreads();
    #pragma unroll
    for (int i = 0; i < 16; i++) p.deg[t*N + base + i] = pre + loc[i];  // cursor
  } else if (gb < 36){
    for (int idx = (gb-4)*256 + tid; idx < N*HD; idx += 32*256){
      float v = ldI(p.h0, idx, f);
      p.h_prev[idx] = v; p.h_bf[idx] = f2b(v);
    }
  } else {
    int u = gb - 36;
    int colblk = u & 3, rowblk = u >> 2;
    mfma_tile(sm.g, tid, f, p.x, 1, XD, XD,
              p.phi_x_w, HD, colblk*64, p.phi_x_b, 1,
              p.phiXa, HD, rowblk*64, colblk*64, nullptr, 0);
  }
}

// precompute h-independent GEMM halves for ALL steps:
// PreB[t][n][0:256]=phiX@enc_w_top, [256:512]=phiX@gxz_top, [512:768]=phiX@gxr_top, [768:1024]=phiX@gxh_top
__global__ __launch_bounds__(256) void setup3_k(KP p){
  __shared__ GemmSM sm;
  int gb = blockIdx.x, tid = threadIdx.x, f = *p.dflag;
  int colblk = gb & 15, rowblk = gb >> 4;        // rowblk over T*N/64 = 256
  int grp = colblk >> 2, c4 = colblk & 3;
  const void* W;
  if (grp == 0) W = p.enc_w;
  else if (grp == 1) W = p.gxz;
  else if (grp == 2) W = p.gxr;
  else W = p.gxh;
  mfma_tile(sm, tid, f, p.phiXa, 2, HD, 256,
            W, HD, c4*64, nullptr, 0,
            p.PreB, 1024, rowblk*64, colblk*64, nullptr, 0);
}

// ---------------- step kernels ----------------
// g1: GEMM tiles (0-1023), all K=256 now (enc phiX-half precomputed); at t==0,
// blocks 1024-2047 perform the edge scatter.
__global__ __launch_bounds__(256) void g1_k(KP p, int t){
  __shared__ GemmSM sm;
  int gb = blockIdx.x, tid = threadIdx.x, f = *p.dflag;
  if (gb >= 1024){
    int idx = (gb - 1024)*256 + tid;      // T*E total
    int tt = idx >> 16, e = idx & (E-1);
    int s = p.ei[(size_t)tt*2*E + e] & (N-1);
    int d = p.ei[(size_t)tt*2*E + E + e] & (N-1);
    int pos = atomicAdd(&p.deg[tt*N + d], 1);
    if (pos >= 0 && pos < E){
      p.srcs[(size_t)tt*E + pos] = s;
      p.enorm[(size_t)tt*E + pos] = p.dinv[tt*N + s] * p.dinv[tt*N + d];
    }
    return;
  }
  const bf16* preT = p.PreB + (size_t)t*N*1024;
  int colblk = gb & 15, rowblk = gb >> 4;
  int grp = colblk >> 2, c4 = colblk & 3;
  if (grp == 0)
    mfma_tile(sm, tid, f, p.h_bf, 2, HD, 256,
              wofs(p.enc_w, f, (size_t)256*HD), HD, c4*64, nullptr, 0,
              p.Gs1, 1024, rowblk*64, colblk*64, preT + c4*64, 1024);
  else if (grp == 1)
    mfma_tile(sm, tid, f, p.h_bf, 2, HD, 256,
              p.prior_w, HD, c4*64, p.prior_b, 1,
              p.Gs1, 1024, rowblk*64, colblk*64, nullptr, 0);
  else if (grp == 2)
    mfma_tile(sm, tid, f, p.h_bf, 2, HD, 256,
              p.ghz, HD, c4*64, nullptr, 0,
              p.Gs1, 1024, rowblk*64, colblk*64, nullptr, 0);
  else
    mfma_tile(sm, tid, f, p.h_bf, 2, HD, 256,
              p.ghr, HD, c4*64, nullptr, 0,
              p.Gs1, 1024, rowblk*64, colblk*64, nullptr, 0);
}

// fused enc: per 16-node block, aggregate Gs1 cols 0-255 (+enc_b, relu) into LDS,
// then 16x128 K=256 MFMA GEMM -> Gms cols 0-127. blocks 256-383: prior mean/std GEMM.
__global__ __launch_bounds__(256) void encfused_k(KP p, int t){   // grid 384
  __shared__ union { EncSM e; GemmSM g; } sm;
  int gb = blockIdx.x, tid = threadIdx.x, f = *p.dflag;
  if (gb >= 256){
    int u = gb - 256;
    int colblk = u & 1, rowblk = u >> 1;
    mfma_tile(sm.g, tid, f, p.Gs1 + 256, 2, 1024, 256,
              colblk ? p.prior_std_w : p.prior_mean_w, ZD, 0,
              colblk ? p.prior_std_b : p.prior_mean_b, 0,
              p.Gms, 256, rowblk*64, 128 + colblk*64, nullptr, 0);
    return;
  }
  const int* offs_t = p.offs + t*(N+1);
  const int* srcs_t = p.srcs + (size_t)t*E;
  const float* en_t = p.enorm + (size_t)t*E;
  const float* dv_t = p.dinv + t*N;
  int g16 = tid >> 4, l = tid & 15;
  int n = gb*16 + g16, c = l*16;
  {
    int e0 = offs_t[n], e1 = offs_t[n+1];
    float d2 = dv_t[n]*dv_t[n];
    float acc[16], va[8], vb[8], vc[8], vd[8];
    ld8b(p.Gs1 + (size_t)n*1024 + c, va);
    ld8b(p.Gs1 + (size_t)n*1024 + c + 8, vb);
    #pragma unroll
    for (int j = 0; j < 8; j++){ acc[j] = d2*va[j]; acc[8+j] = d2*vb[j]; }
    int e = e0;
    for (; e + 1 < e1; e += 2){
      int s0 = srcs_t[e] & (N-1), s1 = srcs_t[e+1] & (N-1);
      float n0 = en_t[e], n1 = en_t[e+1];
      ld8b(p.Gs1 + (size_t)s0*1024 + c, va);
      ld8b(p.Gs1 + (size_t)s0*1024 + c + 8, vb);
      ld8b(p.Gs1 + (size_t)s1*1024 + c, vc);
      ld8b(p.Gs1 + (size_t)s1*1024 + c + 8, vd);
      #pragma unroll
      for (int j = 0; j < 8; j++){ acc[j] += n0*va[j] + n1*vc[j]; acc[8+j] += n0*vb[j] + n1*vd[j]; }
    }
    if (e < e1){
      int s0 = srcs_t[e] & (N-1);
      float n0 = en_t[e];
      ld8b(p.Gs1 + (size_t)s0*1024 + c, va);
      ld8b(p.Gs1 + (size_t)s0*1024 + c + 8, vb);
      #pragma unroll
      for (int j = 0; j < 8; j++){ acc[j] += n0*va[j]; acc[8+j] += n0*vb[j]; }
    }
    #pragma unroll
    for (int j = 0; j < 16; j++) acc[j] = fmaxf(acc[j] + ldI(p.enc_b, c + j, f), 0.f);
    *(uint4*)&sm.e.At[g16*264 + c]     = pack8(acc);
    *(uint4*)&sm.e.At[g16*264 + c + 8] = pack8(acc + 8);
  }
  int wave = tid >> 6, lane = tid & 63, m = lane & 15, kq = lane >> 4;
  int kp2e = (tid >> 4)*2;          // k-pair within 32-chunk (0..30)
  int wn2 = (tid & 15)*8;           // out col 0..120
  f32x4 acc2[2] = {};
  for (int k0 = 0; k0 < 256; k0 += 32){
    const void* Wp = (wn2 < 64) ? p.enc_mean_w : p.enc_std_w;
    int wc = wn2 & 63;
    size_t wi = (size_t)(k0 + kp2e)*ZD + wc;
    short w0[8], w1[8];
    if (f == 0){
      short8 t0 = *(const short8*)((const short*)Wp + wi);
      short8 t1 = *(const short8*)((const short*)Wp + wi + ZD);
      #pragma unroll
      for (int j = 0; j < 8; j++){ w0[j] = t0[j]; w1[j] = t1[j]; }
    } else {
      float wf0[8], wf1[8];
      ldW8(Wp, wi, 1, wf0); ldW8(Wp, wi + ZD, 1, wf1);
      #pragma unroll
      for (int j = 0; j < 8; j++){ w0[j] = f2s(wf0[j]); w1[j] = f2s(wf1[j]); }
    }
    #pragma unroll
    for (int j = 0; j < 8; j++){
      int nrow = wn2 + j;
      int col = (((kp2e >> 3) ^ ((nrow >> 3) & 3)) << 3) | (kp2e & 7);
      *(unsigned int*)&sm.e.Wt[nrow*40 + col] = pack2s(w0[j], w1[j]);
    }
    __syncthreads();
    short8 afr = *(const short8*)&sm.e.At[m*264 + k0 + kq*8];
    #pragma unroll
    for (int t2 = 0; t2 < 2; t2++){
      int nb = wave*32 + t2*16 + m, sb = (nb >> 3) & 3;
      short8 bfr = *(const short8*)&sm.e.Wt[nb*40 + ((kq ^ sb) << 3)];
      acc2[t2] = __builtin_amdgcn_mfma_f32_16x16x32_bf16(afr, bfr, acc2[t2], 0, 0, 0);
    }
    __syncthreads();
  }
  #pragma unroll
  for (int t2 = 0; t2 < 2; t2++){
    int cc = wave*32 + t2*16 + m;
    #pragma unroll
    for (int reg = 0; reg < 4; reg++){
      int node = gb*16 + kq*4 + reg;
      p.Gms[(size_t)node*256 + cc] = f2b(acc2[t2][reg]);
    }
  }
}

// fused: enc mean/std aggregation + reparam + outputs + kld (grid 256)
__global__ __launch_bounds__(256) void msaggpost_k(KP p, int t){
  __shared__ union { float msh[16*132]; float red[256]; } sm;
  int gb = blockIdx.x, tid = threadIdx.x, f = *p.dflag;
  const int* offs_t = p.offs + t*(N+1);
  const int* srcs_t = p.srcs + (size_t)t*E;
  const float* en_t = p.enorm + (size_t)t*E;
  const float* dv_t = p.dinv + t*N;
  int g16 = tid >> 4, l = tid & 15;
  int n = gb*16 + g16, c = l*8;
  {
    int e0 = offs_t[n], e1 = offs_t[n+1];
    float d2 = dv_t[n]*dv_t[n];
    float acc[8], va[8], vb[8];
    ld8b(p.Gms + (size_t)n*256 + c, va);
    #pragma unroll
    for (int j = 0; j < 8; j++) acc[j] = d2 * va[j];
    int e = e0;
    for (; e + 1 < e1; e += 2){
      int s0 = srcs_t[e] & (N-1), s1 = srcs_t[e+1] & (N-1);
      float n0 = en_t[e], n1 = en_t[e+1];
      ld8b(p.Gms + (size_t)s0*256 + c, va);
      ld8b(p.Gms + (size_t)s1*256 + c, vb);
      #pragma unroll
      for (int j = 0; j < 8; j++) acc[j] += n0*va[j] + n1*vb[j];
    }
    if (e < e1){
      int s0 = srcs_t[e] & (N-1);
      float n0 = en_t[e];
      ld8b(p.Gms + (size_t)s0*256 + c, va);
      #pragma unroll
      for (int j = 0; j < 8; j++) acc[j] += n0*va[j];
    }
    #pragma unroll
    for (int j = 0; j < 8; j++) sm.msh[g16*132 + c + j] = acc[j];
  }
  __syncthreads();
  float el = 0.f;
  {
    int d0 = l*4;
    #pragma unroll
    for (int q = 0; q < 4; q++){
      int d = d0 + q;
      size_t idx = (size_t)n*ZD + d;
      float mean = sm.msh[g16*132 + d] + ldI(p.enc_mean_b, d, f);
      float sd = splus(sm.msh[g16*132 + 64 + d] + ldI(p.enc_std_b, d, f));
      float zv = ldI(p.eps, (size_t)t*N*ZD + idx, f)*sd + mean;
      p.zbf[idx] = f2b(zv);
      stO(p.out, OUT_EM + (size_t)t*N*ZD + idx, mean, f);
      float pm = b2f(p.Gms[(size_t)n*256 + 128 + d]);
      float ps = splus(b2f(p.Gms[(size_t)n*256 + 192 + d]));
      stO(p.out, OUT_PM + (size_t)t*N*ZD + idx, pm, f);
      float s1 = sd + 1e-10f, s2 = ps + 1e-10f;
      float dm = mean - pm;
      el += 2.f*(__logf(s2) - __logf(s1)) - (s1*s1 + dm*dm)/(s2*s2) + 1.f;
    }
  }
  __syncthreads();
  sm.red[tid] = el; __syncthreads();
  for (int o = 128; o > 0; o >>= 1){ if (tid < o) sm.red[tid] += sm.red[tid+o]; __syncthreads(); }
  if (tid == 0) atomicAdd(p.scal + 4, sm.red[0] * (0.5f/((float)N*(float)ZD)));
}

__global__ __launch_bounds__(256) void phiz_k(KP p, int t){   // grid 256
  __shared__ GemmSM sm;
  int gb = blockIdx.x, tid = threadIdx.x, f = *p.dflag;
  int colblk = gb & 3, rowblk = gb >> 2;
  mfma_tile(sm, tid, f, p.zbf, 2, ZD, ZD,
            p.phi_z_w, HD, colblk*64, p.phi_z_b, 1,
            p.Tb2, HD, rowblk*64, colblk*64, nullptr, 0);
}

// gru-x GEMM (0-767, K=256 now, phiX half from PreB) + dec tiles (768-4863)
__global__ __launch_bounds__(256) void grux_dec_k(KP p, int t){   // grid 4864
  __shared__ union { GemmSM g; DecSM z; } sm;
  int gb = blockIdx.x, tid = threadIdx.x, f = *p.dflag;
  if (gb < 768){
    int colblk = gb % 12, rowblk = gb / 12;
    int grp = colblk >> 2, c4 = colblk & 3;
    const void* W = (grp == 0) ? p.gxz : ((grp == 1) ? p.gxr : p.gxh);
    mfma_tile(sm.g, tid, f, p.Tb2, 2, HD, 256,
              wofs(W, f, (size_t)256*HD), HD, c4*64, nullptr, 0,
              p.Gsx, 768, rowblk*64, colblk*64,
              p.PreB + (size_t)t*N*1024 + 256 + colblk*64, 1024);
  } else {
    dec_tile1(p, sm.z, tid, t, gb - 768, f);
  }
}

__global__ __launch_bounds__(256) void zr_k(KP p, int t){   // grid 1024
  int gb = blockIdx.x, tid = threadIdx.x;
  const int* offs_t = p.offs + t*(N+1);
  const int* srcs_t = p.srcs + (size_t)t*E;
  const float* en_t = p.enorm + (size_t)t*E;
  const float* dv_t = p.dinv + t*N;
  int g4 = tid >> 6, lane = tid & 63;
  int n = gb*4 + g4, c = lane*8;
  int e0 = offs_t[n], e1 = offs_t[n+1];
  float d2 = dv_t[n]*dv_t[n];
  float acc[8], v1[8], v2[8], v3[8], v4[8];
  ld8b(p.Gsx + (size_t)n*768 + c, v1);
  ld8b(p.Gs1 + 512 + (size_t)n*1024 + c, v2);
  #pragma unroll
  for (int j = 0; j < 8; j++) acc[j] = d2 * (v1[j] + v2[j]);
  int e = e0;
  for (; e + 1 < e1; e += 2){
    int s0 = srcs_t[e] & (N-1), s1 = srcs_t[e+1] & (N-1);
    float n0 = en_t[e], n1 = en_t[e+1];
    ld8b(p.Gsx + (size_t)s0*768 + c, v1);
    ld8b(p.Gs1 + 512 + (size_t)s0*1024 + c, v2);
    ld8b(p.Gsx + (size_t)s1*768 + c, v3);
    ld8b(p.Gs1 + 512 + (size_t)s1*1024 + c, v4);
    #pragma unroll
    for (int j = 0; j < 8; j++) acc[j] += n0*(v1[j] + v2[j]) + n1*(v3[j] + v4[j]);
  }
  if (e < e1){
    int s0 = srcs_t[e] & (N-1);
    float n0 = en_t[e];
    ld8b(p.Gsx + (size_t)s0*768 + c, v1);
    ld8b(p.Gs1 + 512 + (size_t)s0*1024 + c, v2);
    #pragma unroll
    for (int j = 0; j < 8; j++) acc[j] += n0*(v1[j] + v2[j]);
  }
  if (c < 256){
    size_t base = (size_t)n*HD + c;
    float4 o0, o1;
    o0.x = sigm(acc[0]); o0.y = sigm(acc[1]); o0.z = sigm(acc[2]); o0.w = sigm(acc[3]);
    o1.x = sigm(acc[4]); o1.y = sigm(acc[5]); o1.z = sigm(acc[6]); o1.w = sigm(acc[7]);
    *(float4*)(p.z_g + base) = o0;
    *(float4*)(p.z_g + base + 4) = o1;
  } else {
    size_t base = (size_t)n*HD + (c - 256);
    float r[8];
    #pragma unroll
    for (int j = 0; j < 8; j++) r[j] = sigm(acc[j]) * p.h_prev[base+j];
    *(uint4*)(p.Tb1 + base) = pack8(r);
  }
}

__global__ __launch_bounds__(256) void hh_k(KP p, int t){   // grid 256
  __shared__ GemmSM sm;
  int gb = blockIdx.x, tid = threadIdx.x, f = *p.dflag;
  int colblk = gb & 3, rowblk = gb >> 2;
  mfma_tile(sm, tid, f, p.Tb1, 2, HD, 256,
            p.ghh, HD, colblk*64, nullptr, 0,
            p.Gh2, 256, rowblk*64, colblk*64, nullptr, 0);
}

// h update (0-511); at t==3, block 512 finalizes kld/nll outputs
__global__ __launch_bounds__(256) void hagg_k(KP p, int t){
  int gb = blockIdx.x, tid = threadIdx.x, f = *p.dflag;
  if (gb >= 512){
    if (tid == 0){
      const float NNf = 16777216.f;
      float nll = 0.f;
      for (int tt = 0; tt < T_STEPS; tt++){
        float ts = p.scal[8+tt], P = p.scal[12+tt], Q = p.scal[16+tt];
        float posw = (NNf - ts)/ts;
        nll += (posw*P + Q) * 0.5f/(NNf - ts);
      }
      stO(p.out, 0, p.scal[4], f);
      stO(p.out, 1, nll, f);
    }
    return;
  }
  const int* offs_t = p.offs + t*(N+1);
  const int* srcs_t = p.srcs + (size_t)t*E;
  const float* en_t = p.enorm + (size_t)t*E;
  const float* dv_t = p.dinv + t*N;
  int g8 = tid >> 5, l = tid & 31;
  int n = gb*8 + g8, c = l*8;
  int e0 = offs_t[n], e1 = offs_t[n+1];
  float d2 = dv_t[n]*dv_t[n];
  float acc[8], v1[8], v2[8], v3[8], v4[8];
  ld8b(p.Gsx + 512 + (size_t)n*768 + c, v1);
  ld8b(p.Gh2 + (size_t)n*256 + c, v2);
  #pragma unroll
  for (int j = 0; j < 8; j++) acc[j] = d2 * (v1[j] + v2[j]);
  int e = e0;
  for (; e + 1 < e1; e += 2){
    int s0 = srcs_t[e] & (N-1), s1 = srcs_t[e+1] & (N-1);
    float n0 = en_t[e], n1 = en_t[e+1];
    ld8b(p.Gsx + 512 + (size_t)s0*768 + c, v1);
    ld8b(p.Gh2 + (size_t)s0*256 + c, v2);
    ld8b(p.Gsx + 512 + (size_t)s1*768 + c, v3);
    ld8b(p.Gh2 + (size_t)s1*256 + c, v4);
    #pragma unroll
    for (int j = 0; j < 8; j++) acc[j] += n0*(v1[j] + v2[j]) + n1*(v3[j] + v4[j]);
  }
  if (e < e1){
    int s0 = srcs_t[e] & (N-1);
    float n0 = en_t[e];
    ld8b(p.Gsx + 512 + (size_t)s0*768 + c, v1);
    ld8b(p.Gh2 + (size_t)s0*256 + c, v2);
    #pragma unroll
    for (int j = 0; j < 8; j++) acc[j] += n0*(v1[j] + v2[j]);
  }
  size_t base = (size_t)n*HD + c;
  #pragma unroll
  for (int j = 0; j < 8; j++){
    float z = p.z_g[base+j];
    float hv = p.h_prev[base+j];
    float nv = z*hv + (1.f - z)*ftanh(acc[j]);
    p.h_prev[base+j] = nv;
    p.h_bf[base+j] = f2b(nv);
    if (t == T_STEPS-1) stO(p.out, OUT_H + base + j, nv, f);
  }
}

// ---------------- host ----------------
extern "C" void kernel_launch(void* const* d_in, const int* in_sizes, int n_in,
                              void* d_out, int out_size, void* d_ws, size_t ws_size,
                              hipStream_t stream){
  KP P;
  P.x = d_in[0];  P.ei = (const int*)d_in[1];  P.adj = d_in[2];  P.eps = d_in[3];  P.h0 = d_in[4];
  P.phi_x_w = d_in[5];  P.phi_x_b = d_in[6];  P.phi_z_w = d_in[7];  P.phi_z_b = d_in[8];
  P.enc_w = d_in[9];  P.enc_b = d_in[10];
  P.enc_mean_w = d_in[11];  P.enc_mean_b = d_in[12];
  P.enc_std_w = d_in[13];   P.enc_std_b = d_in[14];
  P.prior_w = d_in[15];  P.prior_b = d_in[16];
  P.prior_mean_w = d_in[17];  P.prior_mean_b = d_in[18];
  P.prior_std_w = d_in[19];   P.prior_std_b = d_in[20];
  P.gxz = d_in[21];  P.ghz = d_in[22];  P.gxr = d_in[23];
  P.ghr = d_in[24];  P.gxh = d_in[25];  P.ghh = d_in[26];
  P.out = d_out;

  char* wp = (char*)d_ws;
  auto alloc = [&](size_t bytes){ void* q = (void*)wp; wp += (bytes + 255) & ~(size_t)255; return q; };
  P.scal  = (float*)alloc(64*sizeof(float));
  P.dflag = (int*)  alloc(256);
  P.dinv  = (float*)alloc((size_t)T_STEPS*N*4);
  P.offs  = (int*)  alloc((size_t)T_STEPS*(N+1)*4);
  P.srcs  = (int*)  alloc((size_t)T_STEPS*E*4);
  P.enorm = (float*)alloc((size_t)T_STEPS*E*4);
  P.deg   = (int*)  alloc((size_t)T_STEPS*N*4);
  P.h_prev= (float*)alloc((size_t)N*HD*4);
  P.h_bf  = (bf16*) alloc((size_t)N*HD*2);
  P.phiXa = (bf16*) alloc((size_t)T_STEPS*N*HD*2);
  P.Tb1   = (bf16*) alloc((size_t)N*HD*2);
  P.Tb2   = (bf16*) alloc((size_t)N*HD*2);
  P.zbf   = (bf16*) alloc((size_t)N*ZD*2);
  P.z_g   = (float*)alloc((size_t)N*HD*4);
  P.Gs1   = (bf16*) alloc((size_t)N*1024*2);
  P.Gsx   = (bf16*) alloc((size_t)N*768*2);
  P.Gms   = (bf16*) alloc((size_t)N*256*2);
  P.Gh2   = (bf16*) alloc((size_t)N*256*2);
  P.PreB  = (bf16*) alloc((size_t)T_STEPS*N*1024*2);

  setup0_k<<<66,256,0,stream>>>(P);
  count_deg_k<<<1024,256,0,stream>>>(P);
  setup2_k<<<1060,256,0,stream>>>(P);
  setup3_k<<<4096,256,0,stream>>>(P);
  for (int t = 0; t < T_STEPS; t++){
    g1_k<<<(t == 0) ? 2048 : 1024,256,0,stream>>>(P, t);   // t=0 carries edge scatter
    encfused_k<<<384,256,0,stream>>>(P, t);
    msaggpost_k<<<256,256,0,stream>>>(P, t);
    phiz_k<<<256,256,0,stream>>>(P, t);
    grux_dec_k<<<4864,256,0,stream>>>(P, t);
    zr_k<<<1024,256,0,stream>>>(P, t);
    hh_k<<<256,256,0,stream>>>(P, t);
    hagg_k<<<(t == T_STEPS-1) ? 513 : 512,256,0,stream>>>(P, t);
  }
}

// Round 3
// 1277.339 us; speedup vs baseline: 1.0971x; 1.0261x over previous
//
#include <hip/hip_runtime.h>
#include <hip/hip_bf16.h>

#define T_STEPS 4
#define N 4096
#define E 65536
#define XD 256
#define HD 256
#define ZD 64

typedef __hip_bfloat16 bf16;
typedef __attribute__((ext_vector_type(8))) short short8;
typedef __attribute__((ext_vector_type(4))) float f32x4;

__device__ __forceinline__ float b2f(bf16 v){ return __bfloat162float(v); }
__device__ __forceinline__ bf16 f2b(float v){ return __float2bfloat16(v); }
__device__ __forceinline__ short f2s(float v){ return __builtin_bit_cast(short, f2b(v)); }
__device__ __forceinline__ float bits2f(unsigned int s){ return __builtin_bit_cast(float, s << 16); }
__device__ __forceinline__ float s2f(short s){ return bits2f((unsigned int)(unsigned short)s); }
// fast transcendentals (HW exp2/log2 based; ~1e-6 rel err — far under the 6e-2 threshold)
__device__ __forceinline__ float splus(float x){ return (x > 15.f) ? x : __logf(1.f + __expf(x)); }
__device__ __forceinline__ float sigm(float x){ return 1.f/(1.f + __expf(-x)); }
__device__ __forceinline__ float ftanh(float x){ return 2.f/(1.f + __expf(-2.f*x)) - 1.f; }

__device__ __forceinline__ float ldI(const void* p, size_t i, int f){
  return f ? ((const float*)p)[i] : b2f(((const bf16*)p)[i]);
}
__device__ __forceinline__ void stO(void* p, size_t i, float v, int f){
  if (f) ((float*)p)[i] = v; else ((bf16*)p)[i] = f2b(v);
}
__device__ __forceinline__ void ld8b(const bf16* p, float v[8]){
  uint4 u = *(const uint4*)p;
  v[0]=bits2f(u.x & 0xffffu); v[1]=bits2f(u.x >> 16);
  v[2]=bits2f(u.y & 0xffffu); v[3]=bits2f(u.y >> 16);
  v[4]=bits2f(u.z & 0xffffu); v[5]=bits2f(u.z >> 16);
  v[6]=bits2f(u.w & 0xffffu); v[7]=bits2f(u.w >> 16);
}
__device__ __forceinline__ void ldW8(const void* W, size_t off, int f, float w[8]){
  if (f == 0){ ld8b((const bf16*)W + off, w); }
  else {
    const float* Wf = (const float*)W + off;
    float4 a = *(const float4*)Wf, b = *(const float4*)(Wf + 4);
    w[0]=a.x; w[1]=a.y; w[2]=a.z; w[3]=a.w; w[4]=b.x; w[5]=b.y; w[6]=b.z; w[7]=b.w;
  }
}
__device__ __forceinline__ unsigned int pack2(float a, float b){
  return (unsigned int)(unsigned short)__builtin_bit_cast(unsigned short, f2b(a))
       | ((unsigned int)(unsigned short)__builtin_bit_cast(unsigned short, f2b(b)) << 16);
}
__device__ __forceinline__ uint4 pack8(const float v[8]){
  uint4 o; o.x = pack2(v[0],v[1]); o.y = pack2(v[2],v[3]);
  o.z = pack2(v[4],v[5]); o.w = pack2(v[6],v[7]);
  return o;
}
__device__ __forceinline__ unsigned int pack2s(short a, short b){
  return (unsigned int)(unsigned short)a | ((unsigned int)(unsigned short)b << 16);
}
__device__ __forceinline__ const void* wofs(const void* W, int f, size_t elems){
  return f ? (const void*)((const float*)W + elems) : (const void*)((const bf16*)W + elems);
}

// per-kernel shared structs
struct GemmSM { short As[64*72]; short Wt[64*72]; };                     // 18.4 KB
struct DecSM  { short Zi[64*72]; short Zj[64*72]; short Adj[64*72];
                float redw[12]; };                                       // 27.7 KB
struct EncSM  { short At[16*264]; short Wt[128*40]; };                   // 18.7 KB

struct KP {
  const void *x, *adj, *eps, *h0;
  const int* ei;
  const void *phi_x_w, *phi_x_b, *phi_z_w, *phi_z_b;
  const void *enc_w, *enc_b, *enc_mean_w, *enc_mean_b, *enc_std_w, *enc_std_b;
  const void *prior_w, *prior_b, *prior_mean_w, *prior_mean_b, *prior_std_w, *prior_std_b;
  const void *gxz, *ghz, *gxr, *ghr, *gxh, *ghh;
  void* out;
  float* scal; int* dflag; float* dinv; int* offs; int* srcs; float* enorm; int* deg;
  float* h_prev; bf16* h_bf; bf16* phiXa; bf16* Tb1; bf16* Tb2;
  bf16* zbf; float* z_g; bf16* Gs1; bf16* Gsx; bf16* Gms; bf16* Gh2;
  bf16* PreB;     // T x N x 1024 precomputed phiX @ [enc_top | gxz_top | gxr_top | gxh_top]
};

#define OUT_EM ((size_t)2)
#define OUT_PM ((size_t)(2 + (size_t)T_STEPS*N*ZD))
#define OUT_H  ((size_t)(2 + (size_t)2*T_STEPS*N*ZD))

// ---------------- MFMA 64x64 tile: C = A @ W(+bias)(+pre)(+pre2)(+relu), bf16 out --------
__device__ void mfma_tile(GemmSM& sm, int tid, int f,
    const void* A, int am, int lda, int K,
    const void* W, int ldw, int wcol,
    const void* bias, int act, bf16* C, int ldc, int row0, int ccol0,
    const bf16* pre, int ldpre, const bf16* pre2, int ldpre2){
  int ar = tid >> 2, akk = (tid & 3)*16;          // A: 64 rows x 64 k, 16 elems/thread
  int kp2 = (tid >> 3)*2, wn = (tid & 7)*8;       // W: k rows kp2,kp2+1 (64 k), 8 cols
  int wave = tid >> 6, lane = tid & 63, m = lane & 15, kq = lane >> 4;
  f32x4 acc[4] = {};
  for (int k0 = 0; k0 < K; k0 += 64){
    size_t aidx = (size_t)(row0 + ar)*lda + k0 + akk;
    short8 av0, av1;
    if (am == 2 || f == 0){
      av0 = *(const short8*)((const short*)A + aidx);
      av1 = *(const short8*)((const short*)A + aidx + 8);
    } else {
      const float* Af = (const float*)A + aidx;
      float4 u0 = *(const float4*)(Af);
      float4 u1 = *(const float4*)(Af + 4);
      float4 u2 = *(const float4*)(Af + 8);
      float4 u3 = *(const float4*)(Af + 12);
      av0[0]=f2s(u0.x); av0[1]=f2s(u0.y); av0[2]=f2s(u0.z); av0[3]=f2s(u0.w);
      av0[4]=f2s(u1.x); av0[5]=f2s(u1.y); av0[6]=f2s(u1.z); av0[7]=f2s(u1.w);
      av1[0]=f2s(u2.x); av1[1]=f2s(u2.y); av1[2]=f2s(u2.z); av1[3]=f2s(u2.w);
      av1[4]=f2s(u3.x); av1[5]=f2s(u3.y); av1[6]=f2s(u3.z); av1[7]=f2s(u3.w);
    }
    size_t wi = (size_t)(k0 + kp2)*ldw + wcol + wn;
    short w0[8], w1[8];
    if (f == 0){
      short8 t0 = *(const short8*)((const short*)W + wi);
      short8 t1 = *(const short8*)((const short*)W + wi + ldw);
      #pragma unroll
      for (int j = 0; j < 8; j++){ w0[j] = t0[j]; w1[j] = t1[j]; }
    } else {
      float wf0[8], wf1[8];
      ldW8(W, wi, 1, wf0); ldW8(W, wi + ldw, 1, wf1);
      #pragma unroll
      for (int j = 0; j < 8; j++){ w0[j] = f2s(wf0[j]); w1[j] = f2s(wf1[j]); }
    }
    *(short8*)&sm.As[ar*72 + akk]     = av0;
    *(short8*)&sm.As[ar*72 + akk + 8] = av1;
    #pragma unroll
    for (int j = 0; j < 8; j++){
      int nrow = wn + j;
      int col = (((kp2 >> 3) ^ ((nrow >> 3) & 7)) << 3) | (kp2 & 7);
      *(unsigned int*)&sm.Wt[nrow*72 + col] = pack2s(w0[j], w1[j]);
    }
    __syncthreads();
    short8 afr0 = *(const short8*)&sm.As[(wave*16 + m)*72 + kq*8];
    short8 afr1 = *(const short8*)&sm.As[(wave*16 + m)*72 + (kq + 4)*8];
    #pragma unroll
    for (int t4 = 0; t4 < 4; t4++){
      int nb = t4*16 + m, sb = (nb >> 3) & 7;
      short8 b0 = *(const short8*)&sm.Wt[nb*72 + ((kq ^ sb) << 3)];
      short8 b1 = *(const short8*)&sm.Wt[nb*72 + (((kq + 4) ^ sb) << 3)];
      acc[t4] = __builtin_amdgcn_mfma_f32_16x16x32_bf16(afr0, b0, acc[t4], 0, 0, 0);
      acc[t4] = __builtin_amdgcn_mfma_f32_16x16x32_bf16(afr1, b1, acc[t4], 0, 0, 0);
    }
    __syncthreads();
  }
  #pragma unroll
  for (int t4 = 0; t4 < 4; t4++){
    int c = ccol0 + t4*16 + m;
    float bv = bias ? ldI(bias, wcol + t4*16 + m, f) : 0.f;
    #pragma unroll
    for (int reg = 0; reg < 4; reg++){
      int r = row0 + wave*16 + kq*4 + reg;
      float v = acc[t4][reg] + bv;
      if (pre)  v += b2f(pre [(size_t)r*ldpre  + t4*16 + m]);
      if (pre2) v += b2f(pre2[(size_t)r*ldpre2 + t4*16 + m]);
      if (act == 1) v = fmaxf(v, 0.f);
      C[(size_t)r*ldc + c] = f2b(v);
    }
  }
}

// ---------------- dec 64x64 tile via MFMA, adj through LDS, fused 3-way reduce ------------
__device__ void dec_tile1(const KP& p, DecSM& d, int tid, int t, int u, int f){
  int i0 = (u >> 6)*64, j0 = (u & 63)*64;
  size_t aoff = (size_t)t*N*N;
  #pragma unroll
  for (int i = 0; i < 2; i++){
    int idx = tid + i*256;
    int r = idx >> 3, c = idx & 7;
    int col = ((c ^ ((r >> 3) & 3)) << 3);
    *(short8*)&d.Zi[r*72 + col] = *(const short8*)((const short*)p.zbf + (size_t)(i0+r)*ZD + c*8);
    *(short8*)&d.Zj[r*72 + col] = *(const short8*)((const short*)p.zbf + (size_t)(j0+r)*ZD + c*8);
  }
  {
    int row = tid >> 2, c0 = (tid & 3)*16;
    if (f){
      const float* ap = (const float*)p.adj + aoff + (size_t)(i0+row)*N + j0 + c0;
      short tmp[16];
      #pragma unroll
      for (int q = 0; q < 16; q += 4){
        float4 v = *(const float4*)(ap + q);
        tmp[q]=f2s(v.x); tmp[q+1]=f2s(v.y); tmp[q+2]=f2s(v.z); tmp[q+3]=f2s(v.w);
      }
      *(short8*)&d.Adj[row*72 + c0]     = *(short8*)&tmp[0];
      *(short8*)&d.Adj[row*72 + c0 + 8] = *(short8*)&tmp[8];
    } else {
      const short* ap = (const short*)p.adj + aoff + (size_t)(i0+row)*N + j0 + c0;
      *(short8*)&d.Adj[row*72 + c0]     = *(const short8*)ap;
      *(short8*)&d.Adj[row*72 + c0 + 8] = *(const short8*)(ap + 8);
    }
  }
  __syncthreads();
  int wave = tid >> 6, lane = tid & 63, m = lane & 15, kq = lane >> 4;
  int ra = wave*16 + m, sa = (ra >> 3) & 3;
  short8 a1 = *(const short8*)&d.Zi[ra*72 + ((kq ^ sa) << 3)];
  short8 a2 = *(const short8*)&d.Zi[ra*72 + (((kq+4) ^ sa) << 3)];
  f32x4 acc[4] = {};
  #pragma unroll
  for (int t4 = 0; t4 < 4; t4++){
    int rb = t4*16 + m, sb2 = (rb >> 3) & 3;
    short8 b1 = *(const short8*)&d.Zj[rb*72 + ((kq ^ sb2) << 3)];
    short8 b2 = *(const short8*)&d.Zj[rb*72 + (((kq+4) ^ sb2) << 3)];
    acc[t4] = __builtin_amdgcn_mfma_f32_16x16x32_bf16(a1, b1, acc[t4], 0, 0, 0);
    acc[t4] = __builtin_amdgcn_mfma_f32_16x16x32_bf16(a2, b2, acc[t4], 0, 0, 0);
  }
  float lts = 0.f, lP = 0.f, lQ = 0.f;
  #pragma unroll
  for (int t4 = 0; t4 < 4; t4++){
    int lj = t4*16 + m;
    #pragma unroll
    for (int reg = 0; reg < 4; reg++){
      int li = wave*16 + kq*4 + reg;
      float av = s2f(d.Adj[li*72 + lj]);
      float dec = sigm(acc[t4][reg]);
      lts += av;
      lQ += (1.f - av)*splus(dec);
      if (av != 0.f) lP += av*splus(-dec);
    }
  }
  // wave-level butterfly reduce (no barrier tree)
  #pragma unroll
  for (int off = 32; off > 0; off >>= 1){
    lts += __shfl_xor(lts, off);
    lP  += __shfl_xor(lP,  off);
    lQ  += __shfl_xor(lQ,  off);
  }
  if (lane == 0){ d.redw[wave] = lts; d.redw[4+wave] = lP; d.redw[8+wave] = lQ; }
  __syncthreads();
  if (tid == 0){
    atomicAdd(p.scal + 8 + t,  d.redw[0]+d.redw[1]+d.redw[2]+d.redw[3]);
    atomicAdd(p.scal + 12 + t, d.redw[4]+d.redw[5]+d.redw[6]+d.redw[7]);
    atomicAdd(p.scal + 16 + t, d.redw[8]+d.redw[9]+d.redw[10]+d.redw[11]);
  }
}

// ---------------- setup kernels ----------------
__global__ __launch_bounds__(256) void setup0_k(KP p){
  int gb = blockIdx.x, tid = threadIdx.x;
  if (gb == 0){ if (tid < 64) p.scal[tid] = 0.f; }
  else if (gb == 1){
    if (tid == 0){
      const unsigned short* u = (const unsigned short*)p.x;
      int big = 0;
      for (int i = 0; i < 256; i++){ int e = (u[i] >> 7) & 0xFF; if (e >= 134) big++; }
      *p.dflag = (big > 16) ? 1 : 0;
    }
  } else {
    p.deg[(gb-2)*256 + tid] = 0;
  }
}

__global__ __launch_bounds__(256) void count_deg_k(KP p){
  int idx = blockIdx.x*256 + threadIdx.x;
  int t = idx >> 16, e = idx & (E-1);
  int dst = p.ei[(size_t)t*2*E + E + e] & (N-1);
  atomicAdd(&p.deg[t*N + dst], 1);
}

// scan+cursor (0-3) + h0 copy (4-35) + phi_x GEMM (36-1059)
__global__ __launch_bounds__(256) void setup2_k(KP p){
  __shared__ union { int sh[256]; GemmSM g; } sm;
  int gb = blockIdx.x, tid = threadIdx.x;
  int f = *p.dflag;
  if (gb < 4){
    int t = gb;
    const int* dg = p.deg + t*N;
    int* of = p.offs + t*(N+1);
    int base = tid*16;
    int loc[16]; int s = 0;
    #pragma unroll
    for (int i = 0; i < 16; i++){ loc[i] = s; s += dg[base+i]; }
    sm.sh[tid] = s;
    __syncthreads();
    for (int o = 1; o < 256; o <<= 1){
      int v = (tid >= o) ? sm.sh[tid-o] : 0;
      __syncthreads();
      sm.sh[tid] += v;
      __syncthreads();
    }
    int pre = (tid == 0) ? 0 : sm.sh[tid-1];
    #pragma unroll
    for (int i = 0; i < 16; i++){
      int deg_i = dg[base+i];
      of[base+i] = pre + loc[i];
      p.dinv[t*N + base + i] = rsqrtf(1.f + (float)deg_i);
    }
    if (tid == 255) of[N] = sm.sh[255];
    __syncthreads();
    #pragma unroll
    for (int i = 0; i < 16; i++) p.deg[t*N + base + i] = pre + loc[i];  // cursor
  } else if (gb < 36){
    for (int idx = (gb-4)*256 + tid; idx < N*HD; idx += 32*256){
      float v = ldI(p.h0, idx, f);
      p.h_prev[idx] = v; p.h_bf[idx] = f2b(v);
    }
  } else {
    int u = gb - 36;
    int colblk = u & 3, rowblk = u >> 2;
    mfma_tile(sm.g, tid, f, p.x, 1, XD, XD,
              p.phi_x_w, HD, colblk*64, p.phi_x_b, 1,
              p.phiXa, HD, rowblk*64, colblk*64, nullptr, 0, nullptr, 0);
  }
}

// precompute h-independent GEMM halves for ALL steps:
// PreB[t][n][0:256]=phiX@enc_w_top, [256:512]=phiX@gxz_top, [512:768]=phiX@gxr_top, [768:1024]=phiX@gxh_top
__global__ __launch_bounds__(256) void setup3_k(KP p){
  __shared__ GemmSM sm;
  int gb = blockIdx.x, tid = threadIdx.x, f = *p.dflag;
  int colblk = gb & 15, rowblk = gb >> 4;        // rowblk over T*N/64 = 256
  int grp = colblk >> 2, c4 = colblk & 3;
  const void* W;
  if (grp == 0) W = p.enc_w;
  else if (grp == 1) W = p.gxz;
  else if (grp == 2) W = p.gxr;
  else W = p.gxh;
  mfma_tile(sm, tid, f, p.phiXa, 2, HD, 256,
            W, HD, c4*64, nullptr, 0,
            p.PreB, 1024, rowblk*64, colblk*64, nullptr, 0, nullptr, 0);
}

// ---------------- step kernels ----------------
// g1: GEMM tiles (0-1023), all K=256; at t==0, blocks 1024-2047 perform the edge scatter.
__global__ __launch_bounds__(256) void g1_k(KP p, int t){
  __shared__ GemmSM sm;
  int gb = blockIdx.x, tid = threadIdx.x, f = *p.dflag;
  if (gb >= 1024){
    int idx = (gb - 1024)*256 + tid;      // T*E total
    int tt = idx >> 16, e = idx & (E-1);
    int s = p.ei[(size_t)tt*2*E + e] & (N-1);
    int d = p.ei[(size_t)tt*2*E + E + e] & (N-1);
    int pos = atomicAdd(&p.deg[tt*N + d], 1);
    if (pos >= 0 && pos < E){
      p.srcs[(size_t)tt*E + pos] = s;
      p.enorm[(size_t)tt*E + pos] = p.dinv[tt*N + s] * p.dinv[tt*N + d];
    }
    return;
  }
  const bf16* preT = p.PreB + (size_t)t*N*1024;
  int colblk = gb & 15, rowblk = gb >> 4;
  int grp = colblk >> 2, c4 = colblk & 3;
  if (grp == 0)
    mfma_tile(sm, tid, f, p.h_bf, 2, HD, 256,
              wofs(p.enc_w, f, (size_t)256*HD), HD, c4*64, nullptr, 0,
              p.Gs1, 1024, rowblk*64, colblk*64, preT + c4*64, 1024, nullptr, 0);
  else if (grp == 1)
    mfma_tile(sm, tid, f, p.h_bf, 2, HD, 256,
              p.prior_w, HD, c4*64, p.prior_b, 1,
              p.Gs1, 1024, rowblk*64, colblk*64, nullptr, 0, nullptr, 0);
  else if (grp == 2)
    mfma_tile(sm, tid, f, p.h_bf, 2, HD, 256,
              p.ghz, HD, c4*64, nullptr, 0,
              p.Gs1, 1024, rowblk*64, colblk*64, nullptr, 0, nullptr, 0);
  else
    mfma_tile(sm, tid, f, p.h_bf, 2, HD, 256,
              p.ghr, HD, c4*64, nullptr, 0,
              p.Gs1, 1024, rowblk*64, colblk*64, nullptr, 0, nullptr, 0);
}

// fused enc: per 16-node block, aggregate Gs1 cols 0-255 (+enc_b, relu) into LDS,
// then 16x128 K=256 MFMA GEMM -> Gms cols 0-127. blocks 256-383: prior mean/std GEMM.
__global__ __launch_bounds__(256) void encfused_k(KP p, int t){   // grid 384
  __shared__ union { EncSM e; GemmSM g; } sm;
  int gb = blockIdx.x, tid = threadIdx.x, f = *p.dflag;
  if (gb >= 256){
    int u = gb - 256;
    int colblk = u & 1, rowblk = u >> 1;
    mfma_tile(sm.g, tid, f, p.Gs1 + 256, 2, 1024, 256,
              colblk ? p.prior_std_w : p.prior_mean_w, ZD, 0,
              colblk ? p.prior_std_b : p.prior_mean_b, 0,
              p.Gms, 256, rowblk*64, 128 + colblk*64, nullptr, 0, nullptr, 0);
    return;
  }
  const int* offs_t = p.offs + t*(N+1);
  const int* srcs_t = p.srcs + (size_t)t*E;
  const float* en_t = p.enorm + (size_t)t*E;
  const float* dv_t = p.dinv + t*N;
  int g16 = tid >> 4, l = tid & 15;
  int n = gb*16 + g16, c = l*16;
  {
    int e0 = offs_t[n], e1 = offs_t[n+1];
    float d2 = dv_t[n]*dv_t[n];
    float acc[16], va[8], vb[8], vc[8], vd[8];
    ld8b(p.Gs1 + (size_t)n*1024 + c, va);
    ld8b(p.Gs1 + (size_t)n*1024 + c + 8, vb);
    #pragma unroll
    for (int j = 0; j < 8; j++){ acc[j] = d2*va[j]; acc[8+j] = d2*vb[j]; }
    int e = e0;
    for (; e + 1 < e1; e += 2){
      int s0 = srcs_t[e] & (N-1), s1 = srcs_t[e+1] & (N-1);
      float n0 = en_t[e], n1 = en_t[e+1];
      ld8b(p.Gs1 + (size_t)s0*1024 + c, va);
      ld8b(p.Gs1 + (size_t)s0*1024 + c + 8, vb);
      ld8b(p.Gs1 + (size_t)s1*1024 + c, vc);
      ld8b(p.Gs1 + (size_t)s1*1024 + c + 8, vd);
      #pragma unroll
      for (int j = 0; j < 8; j++){ acc[j] += n0*va[j] + n1*vc[j]; acc[8+j] += n0*vb[j] + n1*vd[j]; }
    }
    if (e < e1){
      int s0 = srcs_t[e] & (N-1);
      float n0 = en_t[e];
      ld8b(p.Gs1 + (size_t)s0*1024 + c, va);
      ld8b(p.Gs1 + (size_t)s0*1024 + c + 8, vb);
      #pragma unroll
      for (int j = 0; j < 8; j++){ acc[j] += n0*va[j]; acc[8+j] += n0*vb[j]; }
    }
    #pragma unroll
    for (int j = 0; j < 16; j++) acc[j] = fmaxf(acc[j] + ldI(p.enc_b, c + j, f), 0.f);
    *(uint4*)&sm.e.At[g16*264 + c]     = pack8(acc);
    *(uint4*)&sm.e.At[g16*264 + c + 8] = pack8(acc + 8);
  }
  int wave = tid >> 6, lane = tid & 63, m = lane & 15, kq = lane >> 4;
  int kp2e = (tid >> 4)*2;          // k-pair within 32-chunk (0..30)
  int wn2 = (tid & 15)*8;           // out col 0..120
  f32x4 acc2[2] = {};
  for (int k0 = 0; k0 < 256; k0 += 32){
    const void* Wp = (wn2 < 64) ? p.enc_mean_w : p.enc_std_w;
    int wc = wn2 & 63;
    size_t wi = (size_t)(k0 + kp2e)*ZD + wc;
    short w0[8], w1[8];
    if (f == 0){
      short8 t0 = *(const short8*)((const short*)Wp + wi);
      short8 t1 = *(const short8*)((const short*)Wp + wi + ZD);
      #pragma unroll
      for (int j = 0; j < 8; j++){ w0[j] = t0[j]; w1[j] = t1[j]; }
    } else {
      float wf0[8], wf1[8];
      ldW8(Wp, wi, 1, wf0); ldW8(Wp, wi + ZD, 1, wf1);
      #pragma unroll
      for (int j = 0; j < 8; j++){ w0[j] = f2s(wf0[j]); w1[j] = f2s(wf1[j]); }
    }
    #pragma unroll
    for (int j = 0; j < 8; j++){
      int nrow = wn2 + j;
      int col = (((kp2e >> 3) ^ ((nrow >> 3) & 3)) << 3) | (kp2e & 7);
      *(unsigned int*)&sm.e.Wt[nrow*40 + col] = pack2s(w0[j], w1[j]);
    }
    __syncthreads();
    short8 afr = *(const short8*)&sm.e.At[m*264 + k0 + kq*8];
    #pragma unroll
    for (int t2 = 0; t2 < 2; t2++){
      int nb = wave*32 + t2*16 + m, sb = (nb >> 3) & 3;
      short8 bfr = *(const short8*)&sm.e.Wt[nb*40 + ((kq ^ sb) << 3)];
      acc2[t2] = __builtin_amdgcn_mfma_f32_16x16x32_bf16(afr, bfr, acc2[t2], 0, 0, 0);
    }
    __syncthreads();
  }
  #pragma unroll
  for (int t2 = 0; t2 < 2; t2++){
    int cc = wave*32 + t2*16 + m;
    #pragma unroll
    for (int reg = 0; reg < 4; reg++){
      int node = gb*16 + kq*4 + reg;
      p.Gms[(size_t)node*256 + cc] = f2b(acc2[t2][reg]);
    }
  }
}

// fused: enc mean/std aggregation + reparam + outputs + kld + phi_z GEMM (grid 256)
__global__ __launch_bounds__(256) void msaggpost_k(KP p, int t){
  __shared__ struct { float msh[16*132]; float red[256];
                      short zsh[16*72]; short Wt[256*72]; } sm;   // 48.6 KB
  int gb = blockIdx.x, tid = threadIdx.x, f = *p.dflag;
  // stage phi_z_w [64][256] into Wt[col][k] (transposed + XOR-swizzled), done once
  {
    int wn = (tid & 31)*8, kb = (tid >> 5)*2;
    for (int ko = 0; ko < 64; ko += 16){
      int kk = kb + ko;
      short w0[8], w1[8];
      if (f == 0){
        short8 t0 = *(const short8*)((const short*)p.phi_z_w + (size_t)kk*HD + wn);
        short8 t1 = *(const short8*)((const short*)p.phi_z_w + (size_t)(kk+1)*HD + wn);
        #pragma unroll
        for (int j = 0; j < 8; j++){ w0[j] = t0[j]; w1[j] = t1[j]; }
      } else {
        float a[8], b[8];
        ldW8(p.phi_z_w, (size_t)kk*HD + wn, 1, a);
        ldW8(p.phi_z_w, (size_t)(kk+1)*HD + wn, 1, b);
        #pragma unroll
        for (int j = 0; j < 8; j++){ w0[j] = f2s(a[j]); w1[j] = f2s(b[j]); }
      }
      #pragma unroll
      for (int j = 0; j < 8; j++){
        int nrow = wn + j;
        int pos = (((kk >> 3) ^ ((nrow >> 3) & 7)) << 3) | (kk & 7);
        *(unsigned int*)&sm.Wt[nrow*72 + pos] = pack2s(w0[j], w1[j]);
      }
    }
  }
  const int* offs_t = p.offs + t*(N+1);
  const int* srcs_t = p.srcs + (size_t)t*E;
  const float* en_t = p.enorm + (size_t)t*E;
  const float* dv_t = p.dinv + t*N;
  int g16 = tid >> 4, l = tid & 15;
  int n = gb*16 + g16, c = l*8;
  {
    int e0 = offs_t[n], e1 = offs_t[n+1];
    float d2 = dv_t[n]*dv_t[n];
    float acc[8], va[8], vb[8];
    ld8b(p.Gms + (size_t)n*256 + c, va);
    #pragma unroll
    for (int j = 0; j < 8; j++) acc[j] = d2 * va[j];
    int e = e0;
    for (; e + 1 < e1; e += 2){
      int s0 = srcs_t[e] & (N-1), s1 = srcs_t[e+1] & (N-1);
      float n0 = en_t[e], n1 = en_t[e+1];
      ld8b(p.Gms + (size_t)s0*256 + c, va);
      ld8b(p.Gms + (size_t)s1*256 + c, vb);
      #pragma unroll
      for (int j = 0; j < 8; j++) acc[j] += n0*va[j] + n1*vb[j];
    }
    if (e < e1){
      int s0 = srcs_t[e] & (N-1);
      float n0 = en_t[e];
      ld8b(p.Gms + (size_t)s0*256 + c, va);
      #pragma unroll
      for (int j = 0; j < 8; j++) acc[j] += n0*va[j];
    }
    #pragma unroll
    for (int j = 0; j < 8; j++) sm.msh[g16*132 + c + j] = acc[j];
  }
  __syncthreads();
  float el = 0.f;
  {
    int d0 = l*4;
    float z4[4];
    #pragma unroll
    for (int q = 0; q < 4; q++){
      int d = d0 + q;
      size_t idx = (size_t)n*ZD + d;
      float mean = sm.msh[g16*132 + d] + ldI(p.enc_mean_b, d, f);
      float sd = splus(sm.msh[g16*132 + 64 + d] + ldI(p.enc_std_b, d, f));
      float zv = ldI(p.eps, (size_t)t*N*ZD + idx, f)*sd + mean;
      z4[q] = zv;
      p.zbf[idx] = f2b(zv);
      stO(p.out, OUT_EM + (size_t)t*N*ZD + idx, mean, f);
      float pm = b2f(p.Gms[(size_t)n*256 + 128 + d]);
      float ps = splus(b2f(p.Gms[(size_t)n*256 + 192 + d]));
      stO(p.out, OUT_PM + (size_t)t*N*ZD + idx, pm, f);
      float s1 = sd + 1e-10f, s2 = ps + 1e-10f;
      float dm = mean - pm;
      el += 2.f*(__logf(s2) - __logf(s1)) - (s1*s1 + dm*dm)/(s2*s2) + 1.f;
    }
    *(unsigned int*)&sm.zsh[g16*72 + d0]     = pack2(z4[0], z4[1]);
    *(unsigned int*)&sm.zsh[g16*72 + d0 + 2] = pack2(z4[2], z4[3]);
  }
  sm.red[tid] = el;
  __syncthreads();
  // phi_z GEMM: Tb2[gb*16 .. +15][0:256] = relu(z @ phi_z_w + phi_z_b), K=64 single stage
  {
    int wave = tid >> 6, lane = tid & 63, m = lane & 15, kq = lane >> 4;
    short8 a0 = *(const short8*)&sm.zsh[m*72 + kq*8];
    short8 a1 = *(const short8*)&sm.zsh[m*72 + (kq + 4)*8];
    f32x4 pc[4] = {};
    #pragma unroll
    for (int t4 = 0; t4 < 4; t4++){
      int nb = wave*64 + t4*16 + m, sb = (nb >> 3) & 7;
      short8 b0 = *(const short8*)&sm.Wt[nb*72 + ((kq ^ sb) << 3)];
      short8 b1 = *(const short8*)&sm.Wt[nb*72 + (((kq + 4) ^ sb) << 3)];
      pc[t4] = __builtin_amdgcn_mfma_f32_16x16x32_bf16(a0, b0, pc[t4], 0, 0, 0);
      pc[t4] = __builtin_amdgcn_mfma_f32_16x16x32_bf16(a1, b1, pc[t4], 0, 0, 0);
    }
    #pragma unroll
    for (int t4 = 0; t4 < 4; t4++){
      int col = wave*64 + t4*16 + m;
      float bv = ldI(p.phi_z_b, col, f);
      #pragma unroll
      for (int reg = 0; reg < 4; reg++){
        int node = gb*16 + kq*4 + reg;
        p.Tb2[(size_t)node*HD + col] = f2b(fmaxf(pc[t4][reg] + bv, 0.f));
      }
    }
  }
  // kld reduce (red written before the barrier above)
  for (int o = 128; o > 0; o >>= 1){ if (tid < o) sm.red[tid] += sm.red[tid+o]; __syncthreads(); }
  if (tid == 0) atomicAdd(p.scal + 4, sm.red[0] * (0.5f/((float)N*(float)ZD)));
}

// gru-x GEMM (0-767, K=256, phiX half from PreB, h-side gate halves pre-added from Gs1)
// + dec tiles (768-4863)
__global__ __launch_bounds__(256) void grux_dec_k(KP p, int t){   // grid 4864
  __shared__ union { GemmSM g; DecSM z; } sm;
  int gb = blockIdx.x, tid = threadIdx.x, f = *p.dflag;
  if (gb < 768){
    int colblk = gb % 12, rowblk = gb / 12;
    int grp = colblk >> 2, c4 = colblk & 3;
    const void* W = (grp == 0) ? p.gxz : ((grp == 1) ? p.gxr : p.gxh);
    const bf16* pre2 = (grp == 0) ? (p.Gs1 + 512 + c4*64)
                     : (grp == 1) ? (p.Gs1 + 768 + c4*64) : nullptr;
    mfma_tile(sm.g, tid, f, p.Tb2, 2, HD, 256,
              wofs(W, f, (size_t)256*HD), HD, c4*64, nullptr, 0,
              p.Gsx, 768, rowblk*64, colblk*64,
              p.PreB + (size_t)t*N*1024 + 256 + colblk*64, 1024,
              pre2, 1024);
  } else {
    dec_tile1(p, sm.z, tid, t, gb - 768, f);
  }
}

// z/r gates: aggregate Gsx cols 0-511 only (h-side halves pre-summed by grux epilogue)
__global__ __launch_bounds__(256) void zr_k(KP p, int t){   // grid 1024
  int gb = blockIdx.x, tid = threadIdx.x;
  const int* offs_t = p.offs + t*(N+1);
  const int* srcs_t = p.srcs + (size_t)t*E;
  const float* en_t = p.enorm + (size_t)t*E;
  const float* dv_t = p.dinv + t*N;
  int g4 = tid >> 6, lane = tid & 63;
  int n = gb*4 + g4, c = lane*8;
  int e0 = offs_t[n], e1 = offs_t[n+1];
  float d2 = dv_t[n]*dv_t[n];
  float acc[8], v1[8], v2[8];
  ld8b(p.Gsx + (size_t)n*768 + c, v1);
  #pragma unroll
  for (int j = 0; j < 8; j++) acc[j] = d2 * v1[j];
  int e = e0;
  for (; e + 1 < e1; e += 2){
    int s0 = srcs_t[e] & (N-1), s1 = srcs_t[e+1] & (N-1);
    float n0 = en_t[e], n1 = en_t[e+1];
    ld8b(p.Gsx + (size_t)s0*768 + c, v1);
    ld8b(p.Gsx + (size_t)s1*768 + c, v2);
    #pragma unroll
    for (int j = 0; j < 8; j++) acc[j] += n0*v1[j] + n1*v2[j];
  }
  if (e < e1){
    int s0 = srcs_t[e] & (N-1);
    float n0 = en_t[e];
    ld8b(p.Gsx + (size_t)s0*768 + c, v1);
    #pragma unroll
    for (int j = 0; j < 8; j++) acc[j] += n0*v1[j];
  }
  if (c < 256){
    size_t base = (size_t)n*HD + c;
    float4 o0, o1;
    o0.x = sigm(acc[0]); o0.y = sigm(acc[1]); o0.z = sigm(acc[2]); o0.w = sigm(acc[3]);
    o1.x = sigm(acc[4]); o1.y = sigm(acc[5]); o1.z = sigm(acc[6]); o1.w = sigm(acc[7]);
    *(float4*)(p.z_g + base) = o0;
    *(float4*)(p.z_g + base + 4) = o1;
  } else {
    size_t base = (size_t)n*HD + (c - 256);
    float r[8];
    #pragma unroll
    for (int j = 0; j < 8; j++) r[j] = sigm(acc[j]) * p.h_prev[base+j];
    *(uint4*)(p.Tb1 + base) = pack8(r);
  }
}

// (r*h)@ghh, with gin-side xh output (Gsx cols 512-767) pre-added into Gh2
__global__ __launch_bounds__(256) void hh_k(KP p, int t){   // grid 256
  __shared__ GemmSM sm;
  int gb = blockIdx.x, tid = threadIdx.x, f = *p.dflag;
  int colblk = gb & 3, rowblk = gb >> 2;
  mfma_tile(sm, tid, f, p.Tb1, 2, HD, 256,
            p.ghh, HD, colblk*64, nullptr, 0,
            p.Gh2, 256, rowblk*64, colblk*64, nullptr, 0,
            p.Gsx + 512 + colblk*64, 768);
}

// h update: aggregate Gh2 only (0-511); at t==3, block 512 finalizes kld/nll outputs
__global__ __launch_bounds__(256) void hagg_k(KP p, int t){
  int gb = blockIdx.x, tid = threadIdx.x, f = *p.dflag;
  if (gb >= 512){
    if (tid == 0){
      const float NNf = 16777216.f;
      float nll = 0.f;
      for (int tt = 0; tt < T_STEPS; tt++){
        float ts = p.scal[8+tt], P = p.scal[12+tt], Q = p.scal[16+tt];
        float posw = (NNf - ts)/ts;
        nll += (posw*P + Q) * 0.5f/(NNf - ts);
      }
      stO(p.out, 0, p.scal[4], f);
      stO(p.out, 1, nll, f);
    }
    return;
  }
  const int* offs_t = p.offs + t*(N+1);
  const int* srcs_t = p.srcs + (size_t)t*E;
  const float* en_t = p.enorm + (size_t)t*E;
  const float* dv_t = p.dinv + t*N;
  int g8 = tid >> 5, l = tid & 31;
  int n = gb*8 + g8, c = l*8;
  int e0 = offs_t[n], e1 = offs_t[n+1];
  float d2 = dv_t[n]*dv_t[n];
  float acc[8], v1[8], v2[8];
  ld8b(p.Gh2 + (size_t)n*256 + c, v1);
  #pragma unroll
  for (int j = 0; j < 8; j++) acc[j] = d2 * v1[j];
  int e = e0;
  for (; e + 1 < e1; e += 2){
    int s0 = srcs_t[e] & (N-1), s1 = srcs_t[e+1] & (N-1);
    float n0 = en_t[e], n1 = en_t[e+1];
    ld8b(p.Gh2 + (size_t)s0*256 + c, v1);
    ld8b(p.Gh2 + (size_t)s1*256 + c, v2);
    #pragma unroll
    for (int j = 0; j < 8; j++) acc[j] += n0*v1[j] + n1*v2[j];
  }
  if (e < e1){
    int s0 = srcs_t[e] & (N-1);
    float n0 = en_t[e];
    ld8b(p.Gh2 + (size_t)s0*256 + c, v1);
    #pragma unroll
    for (int j = 0; j < 8; j++) acc[j] += n0*v1[j];
  }
  size_t base = (size_t)n*HD + c;
  #pragma unroll
  for (int j = 0; j < 8; j++){
    float z = p.z_g[base+j];
    float hv = p.h_prev[base+j];
    float nv = z*hv + (1.f - z)*ftanh(acc[j]);
    p.h_prev[base+j] = nv;
    p.h_bf[base+j] = f2b(nv);
    if (t == T_STEPS-1) stO(p.out, OUT_H + base + j, nv, f);
  }
}

// ---------------- host ----------------
extern "C" void kernel_launch(void* const* d_in, const int* in_sizes, int n_in,
                              void* d_out, int out_size, void* d_ws, size_t ws_size,
                              hipStream_t stream){
  KP P;
  P.x = d_in[0];  P.ei = (const int*)d_in[1];  P.adj = d_in[2];  P.eps = d_in[3];  P.h0 = d_in[4];
  P.phi_x_w = d_in[5];  P.phi_x_b = d_in[6];  P.phi_z_w = d_in[7];  P.phi_z_b = d_in[8];
  P.enc_w = d_in[9];  P.enc_b = d_in[10];
  P.enc_mean_w = d_in[11];  P.enc_mean_b = d_in[12];
  P.enc_std_w = d_in[13];   P.enc_std_b = d_in[14];
  P.prior_w = d_in[15];  P.prior_b = d_in[16];
  P.prior_mean_w = d_in[17];  P.prior_mean_b = d_in[18];
  P.prior_std_w = d_in[19];   P.prior_std_b = d_in[20];
  P.gxz = d_in[21];  P.ghz = d_in[22];  P.gxr = d_in[23];
  P.ghr = d_in[24];  P.gxh = d_in[25];  P.ghh = d_in[26];
  P.out = d_out;

  char* wp = (char*)d_ws;
  auto alloc = [&](size_t bytes){ void* q = (void*)wp; wp += (bytes + 255) & ~(size_t)255; return q; };
  P.scal  = (float*)alloc(64*sizeof(float));
  P.dflag = (int*)  alloc(256);
  P.dinv  = (float*)alloc((size_t)T_STEPS*N*4);
  P.offs  = (int*)  alloc((size_t)T_STEPS*(N+1)*4);
  P.srcs  = (int*)  alloc((size_t)T_STEPS*E*4);
  P.enorm = (float*)alloc((size_t)T_STEPS*E*4);
  P.deg   = (int*)  alloc((size_t)T_STEPS*N*4);
  P.h_prev= (float*)alloc((size_t)N*HD*4);
  P.h_bf  = (bf16*) alloc((size_t)N*HD*2);
  P.phiXa = (bf16*) alloc((size_t)T_STEPS*N*HD*2);
  P.Tb1   = (bf16*) alloc((size_t)N*HD*2);
  P.Tb2   = (bf16*) alloc((size_t)N*HD*2);
  P.zbf   = (bf16*) alloc((size_t)N*ZD*2);
  P.z_g   = (float*)alloc((size_t)N*HD*4);
  P.Gs1   = (bf16*) alloc((size_t)N*1024*2);
  P.Gsx   = (bf16*) alloc((size_t)N*768*2);
  P.Gms   = (bf16*) alloc((size_t)N*256*2);
  P.Gh2   = (bf16*) alloc((size_t)N*256*2);
  P.PreB  = (bf16*) alloc((size_t)T_STEPS*N*1024*2);

  setup0_k<<<66,256,0,stream>>>(P);
  count_deg_k<<<1024,256,0,stream>>>(P);
  setup2_k<<<1060,256,0,stream>>>(P);
  setup3_k<<<4096,256,0,stream>>>(P);
  for (int t = 0; t < T_STEPS; t++){
    g1_k<<<(t == 0) ? 2048 : 1024,256,0,stream>>>(P, t);   // t=0 carries edge scatter
    encfused_k<<<384,256,0,stream>>>(P, t);
    msaggpost_k<<<256,256,0,stream>>>(P, t);               // + fused phi_z GEMM
    grux_dec_k<<<4864,256,0,stream>>>(P, t);
    zr_k<<<1024,256,0,stream>>>(P, t);
    hh_k<<<256,256,0,stream>>>(P, t);
    hagg_k<<<(t == T_STEPS-1) ? 513 : 512,256,0,stream>>>(P, t);
  }
}

// Round 6
// 1266.832 us; speedup vs baseline: 1.1062x; 1.0083x over previous
//
#include <hip/hip_runtime.h>
#include <hip/hip_bf16.h>

#define T_STEPS 4
#define N 4096
#define E 65536
#define XD 256
#define HD 256
#define ZD 64

typedef __hip_bfloat16 bf16;
typedef __attribute__((ext_vector_type(8))) short short8;
typedef __attribute__((ext_vector_type(4))) float f32x4;

__device__ __forceinline__ float b2f(bf16 v){ return __bfloat162float(v); }
__device__ __forceinline__ bf16 f2b(float v){ return __float2bfloat16(v); }
__device__ __forceinline__ short f2s(float v){ return __builtin_bit_cast(short, f2b(v)); }
__device__ __forceinline__ float bits2f(unsigned int s){ return __builtin_bit_cast(float, s << 16); }
__device__ __forceinline__ float s2f(short s){ return bits2f((unsigned int)(unsigned short)s); }
// fast transcendentals (HW exp2/log2 based; ~1e-6 rel err — far under the 6e-2 threshold)
__device__ __forceinline__ float splus(float x){ return (x > 15.f) ? x : __logf(1.f + __expf(x)); }
__device__ __forceinline__ float sigm(float x){ return 1.f/(1.f + __expf(-x)); }
__device__ __forceinline__ float ftanh(float x){ return 2.f/(1.f + __expf(-2.f*x)) - 1.f; }

__device__ __forceinline__ float ldI(const void* p, size_t i, int f){
  return f ? ((const float*)p)[i] : b2f(((const bf16*)p)[i]);
}
__device__ __forceinline__ void stO(void* p, size_t i, float v, int f){
  if (f) ((float*)p)[i] = v; else ((bf16*)p)[i] = f2b(v);
}
__device__ __forceinline__ void ld8b(const bf16* p, float v[8]){
  uint4 u = *(const uint4*)p;
  v[0]=bits2f(u.x & 0xffffu); v[1]=bits2f(u.x >> 16);
  v[2]=bits2f(u.y & 0xffffu); v[3]=bits2f(u.y >> 16);
  v[4]=bits2f(u.z & 0xffffu); v[5]=bits2f(u.z >> 16);
  v[6]=bits2f(u.w & 0xffffu); v[7]=bits2f(u.w >> 16);
}
__device__ __forceinline__ void ldW8(const void* W, size_t off, int f, float w[8]){
  if (f == 0){ ld8b((const bf16*)W + off, w); }
  else {
    const float* Wf = (const float*)W + off;
    float4 a = *(const float4*)Wf, b = *(const float4*)(Wf + 4);
    w[0]=a.x; w[1]=a.y; w[2]=a.z; w[3]=a.w; w[4]=b.x; w[5]=b.y; w[6]=b.z; w[7]=b.w;
  }
}
__device__ __forceinline__ unsigned int pack2(float a, float b){
  return (unsigned int)(unsigned short)__builtin_bit_cast(unsigned short, f2b(a))
       | ((unsigned int)(unsigned short)__builtin_bit_cast(unsigned short, f2b(b)) << 16);
}
__device__ __forceinline__ uint4 pack8(const float v[8]){
  uint4 o; o.x = pack2(v[0],v[1]); o.y = pack2(v[2],v[3]);
  o.z = pack2(v[4],v[5]); o.w = pack2(v[6],v[7]);
  return o;
}
__device__ __forceinline__ unsigned int pack2s(short a, short b){
  return (unsigned int)(unsigned short)a | ((unsigned int)(unsigned short)b << 16);
}
__device__ __forceinline__ const void* wofs(const void* W, int f, size_t elems){
  return f ? (const void*)((const float*)W + elems) : (const void*)((const bf16*)W + elems);
}

// per-kernel shared structs
struct GemmSM { short As[64*72]; short Wt[64*72]; };                     // 18.4 KB
struct DecSM  { short Zi[64*72]; short Zj[64*72]; short Adj[64*72];
                float redw[12]; };                                       // 27.7 KB
struct EncSM  { short At[16*264]; short Wt[128*40]; };                   // 18.7 KB

struct KP {
  const void *x, *adj, *eps, *h0;
  const int* ei;
  const void *phi_x_w, *phi_x_b, *phi_z_w, *phi_z_b;
  const void *enc_w, *enc_b, *enc_mean_w, *enc_mean_b, *enc_std_w, *enc_std_b;
  const void *prior_w, *prior_b, *prior_mean_w, *prior_mean_b, *prior_std_w, *prior_std_b;
  const void *gxz, *ghz, *gxr, *ghr, *gxh, *ghh;
  void* out;
  float* scal; int* dflag; float* dinv; int* offs; int* srcs; float* enorm; int* deg;
  float* h_prev; bf16* h_bf; bf16* phiXa; bf16* Tb1; bf16* Tb2;
  bf16* zbf; float* z_g; bf16* Gs1; bf16* Gsx; bf16* Gms; bf16* Gh2;
  bf16* PreB;     // T x N x 1024 precomputed phiX @ [enc_top | gxz_top | gxr_top | gxh_top]
};

#define OUT_EM ((size_t)2)
#define OUT_PM ((size_t)(2 + (size_t)T_STEPS*N*ZD))
#define OUT_H  ((size_t)(2 + (size_t)2*T_STEPS*N*ZD))

// ---------------- MFMA 64x64 tile: C = A @ W(+bias)(+pre)(+pre2)(+relu), bf16 out --------
__device__ void mfma_tile(GemmSM& sm, int tid, int f,
    const void* A, int am, int lda, int K,
    const void* W, int ldw, int wcol,
    const void* bias, int act, bf16* C, int ldc, int row0, int ccol0,
    const bf16* pre, int ldpre, const bf16* pre2, int ldpre2){
  int ar = tid >> 2, akk = (tid & 3)*16;          // A: 64 rows x 64 k, 16 elems/thread
  int kp2 = (tid >> 3)*2, wn = (tid & 7)*8;       // W: k rows kp2,kp2+1 (64 k), 8 cols
  int wave = tid >> 6, lane = tid & 63, m = lane & 15, kq = lane >> 4;
  f32x4 acc[4] = {};
  for (int k0 = 0; k0 < K; k0 += 64){
    size_t aidx = (size_t)(row0 + ar)*lda + k0 + akk;
    short8 av0, av1;
    if (am == 2 || f == 0){
      av0 = *(const short8*)((const short*)A + aidx);
      av1 = *(const short8*)((const short*)A + aidx + 8);
    } else {
      const float* Af = (const float*)A + aidx;
      float4 u0 = *(const float4*)(Af);
      float4 u1 = *(const float4*)(Af + 4);
      float4 u2 = *(const float4*)(Af + 8);
      float4 u3 = *(const float4*)(Af + 12);
      av0[0]=f2s(u0.x); av0[1]=f2s(u0.y); av0[2]=f2s(u0.z); av0[3]=f2s(u0.w);
      av0[4]=f2s(u1.x); av0[5]=f2s(u1.y); av0[6]=f2s(u1.z); av0[7]=f2s(u1.w);
      av1[0]=f2s(u2.x); av1[1]=f2s(u2.y); av1[2]=f2s(u2.z); av1[3]=f2s(u2.w);
      av1[4]=f2s(u3.x); av1[5]=f2s(u3.y); av1[6]=f2s(u3.z); av1[7]=f2s(u3.w);
    }
    size_t wi = (size_t)(k0 + kp2)*ldw + wcol + wn;
    short w0[8], w1[8];
    if (f == 0){
      short8 t0 = *(const short8*)((const short*)W + wi);
      short8 t1 = *(const short8*)((const short*)W + wi + ldw);
      #pragma unroll
      for (int j = 0; j < 8; j++){ w0[j] = t0[j]; w1[j] = t1[j]; }
    } else {
      float wf0[8], wf1[8];
      ldW8(W, wi, 1, wf0); ldW8(W, wi + ldw, 1, wf1);
      #pragma unroll
      for (int j = 0; j < 8; j++){ w0[j] = f2s(wf0[j]); w1[j] = f2s(wf1[j]); }
    }
    *(short8*)&sm.As[ar*72 + akk]     = av0;
    *(short8*)&sm.As[ar*72 + akk + 8] = av1;
    #pragma unroll
    for (int j = 0; j < 8; j++){
      int nrow = wn + j;
      int col = (((kp2 >> 3) ^ ((nrow >> 3) & 7)) << 3) | (kp2 & 7);
      *(unsigned int*)&sm.Wt[nrow*72 + col] = pack2s(w0[j], w1[j]);
    }
    __syncthreads();
    short8 afr0 = *(const short8*)&sm.As[(wave*16 + m)*72 + kq*8];
    short8 afr1 = *(const short8*)&sm.As[(wave*16 + m)*72 + (kq + 4)*8];
    #pragma unroll
    for (int t4 = 0; t4 < 4; t4++){
      int nb = t4*16 + m, sb = (nb >> 3) & 7;
      short8 b0 = *(const short8*)&sm.Wt[nb*72 + ((kq ^ sb) << 3)];
      short8 b1 = *(const short8*)&sm.Wt[nb*72 + (((kq + 4) ^ sb) << 3)];
      acc[t4] = __builtin_amdgcn_mfma_f32_16x16x32_bf16(afr0, b0, acc[t4], 0, 0, 0);
      acc[t4] = __builtin_amdgcn_mfma_f32_16x16x32_bf16(afr1, b1, acc[t4], 0, 0, 0);
    }
    __syncthreads();
  }
  #pragma unroll
  for (int t4 = 0; t4 < 4; t4++){
    int c = ccol0 + t4*16 + m;
    float bv = bias ? ldI(bias, wcol + t4*16 + m, f) : 0.f;
    #pragma unroll
    for (int reg = 0; reg < 4; reg++){
      int r = row0 + wave*16 + kq*4 + reg;
      float v = acc[t4][reg] + bv;
      if (pre)  v += b2f(pre [(size_t)r*ldpre  + t4*16 + m]);
      if (pre2) v += b2f(pre2[(size_t)r*ldpre2 + t4*16 + m]);
      if (act == 1) v = fmaxf(v, 0.f);
      C[(size_t)r*ldc + c] = f2b(v);
    }
  }
}

// ---------------- dec 64x64 tile via MFMA, adj through LDS, fused 3-way reduce ------------
__device__ void dec_tile1(const KP& p, DecSM& d, int tid, int t, int u, int f){
  int i0 = (u >> 6)*64, j0 = (u & 63)*64;
  size_t aoff = (size_t)t*N*N;
  #pragma unroll
  for (int i = 0; i < 2; i++){
    int idx = tid + i*256;
    int r = idx >> 3, c = idx & 7;
    int col = ((c ^ ((r >> 3) & 3)) << 3);
    *(short8*)&d.Zi[r*72 + col] = *(const short8*)((const short*)p.zbf + (size_t)(i0+r)*ZD + c*8);
    *(short8*)&d.Zj[r*72 + col] = *(const short8*)((const short*)p.zbf + (size_t)(j0+r)*ZD + c*8);
  }
  {
    int row = tid >> 2, c0 = (tid & 3)*16;
    if (f){
      const float* ap = (const float*)p.adj + aoff + (size_t)(i0+row)*N + j0 + c0;
      short tmp[16];
      #pragma unroll
      for (int q = 0; q < 16; q += 4){
        float4 v = *(const float4*)(ap + q);
        tmp[q]=f2s(v.x); tmp[q+1]=f2s(v.y); tmp[q+2]=f2s(v.z); tmp[q+3]=f2s(v.w);
      }
      *(short8*)&d.Adj[row*72 + c0]     = *(short8*)&tmp[0];
      *(short8*)&d.Adj[row*72 + c0 + 8] = *(short8*)&tmp[8];
    } else {
      const short* ap = (const short*)p.adj + aoff + (size_t)(i0+row)*N + j0 + c0;
      *(short8*)&d.Adj[row*72 + c0]     = *(const short8*)ap;
      *(short8*)&d.Adj[row*72 + c0 + 8] = *(const short8*)(ap + 8);
    }
  }
  __syncthreads();
  int wave = tid >> 6, lane = tid & 63, m = lane & 15, kq = lane >> 4;
  int ra = wave*16 + m, sa = (ra >> 3) & 3;
  short8 a1 = *(const short8*)&d.Zi[ra*72 + ((kq ^ sa) << 3)];
  short8 a2 = *(const short8*)&d.Zi[ra*72 + (((kq+4) ^ sa) << 3)];
  f32x4 acc[4] = {};
  #pragma unroll
  for (int t4 = 0; t4 < 4; t4++){
    int rb = t4*16 + m, sb2 = (rb >> 3) & 3;
    short8 b1 = *(const short8*)&d.Zj[rb*72 + ((kq ^ sb2) << 3)];
    short8 b2 = *(const short8*)&d.Zj[rb*72 + (((kq+4) ^ sb2) << 3)];
    acc[t4] = __builtin_amdgcn_mfma_f32_16x16x32_bf16(a1, b1, acc[t4], 0, 0, 0);
    acc[t4] = __builtin_amdgcn_mfma_f32_16x16x32_bf16(a2, b2, acc[t4], 0, 0, 0);
  }
  float lts = 0.f, lP = 0.f, lQ = 0.f;
  #pragma unroll
  for (int t4 = 0; t4 < 4; t4++){
    int lj = t4*16 + m;
    #pragma unroll
    for (int reg = 0; reg < 4; reg++){
      int li = wave*16 + kq*4 + reg;
      float av = s2f(d.Adj[li*72 + lj]);
      float dec = sigm(acc[t4][reg]);
      lts += av;
      lQ += (1.f - av)*splus(dec);
      if (av != 0.f) lP += av*splus(-dec);
    }
  }
  // wave-level butterfly reduce (no barrier tree)
  #pragma unroll
  for (int off = 32; off > 0; off >>= 1){
    lts += __shfl_xor(lts, off);
    lP  += __shfl_xor(lP,  off);
    lQ  += __shfl_xor(lQ,  off);
  }
  if (lane == 0){ d.redw[wave] = lts; d.redw[4+wave] = lP; d.redw[8+wave] = lQ; }
  __syncthreads();
  if (tid == 0){
    atomicAdd(p.scal + 8 + t,  d.redw[0]+d.redw[1]+d.redw[2]+d.redw[3]);
    atomicAdd(p.scal + 12 + t, d.redw[4]+d.redw[5]+d.redw[6]+d.redw[7]);
    atomicAdd(p.scal + 16 + t, d.redw[8]+d.redw[9]+d.redw[10]+d.redw[11]);
  }
}

// ---------------- setup kernels ----------------
__global__ __launch_bounds__(256) void setup0_k(KP p){
  int gb = blockIdx.x, tid = threadIdx.x;
  if (gb == 0){ if (tid < 64) p.scal[tid] = 0.f; }
  else if (gb == 1){
    if (tid == 0){
      const unsigned short* u = (const unsigned short*)p.x;
      int big = 0;
      for (int i = 0; i < 256; i++){ int e = (u[i] >> 7) & 0xFF; if (e >= 134) big++; }
      *p.dflag = (big > 16) ? 1 : 0;
    }
  } else {
    p.deg[(gb-2)*256 + tid] = 0;
  }
}

__global__ __launch_bounds__(256) void count_deg_k(KP p){
  int idx = blockIdx.x*256 + threadIdx.x;
  int t = idx >> 16, e = idx & (E-1);
  int dst = p.ei[(size_t)t*2*E + E + e] & (N-1);
  atomicAdd(&p.deg[t*N + dst], 1);
}

// scan+cursor (0-3) + h0 copy (4-35) + phi_x GEMM (36-1059)
__global__ __launch_bounds__(256) void setup2_k(KP p){
  __shared__ union { int sh[256]; GemmSM g; } sm;
  int gb = blockIdx.x, tid = threadIdx.x;
  int f = *p.dflag;
  if (gb < 4){
    int t = gb;
    const int* dg = p.deg + t*N;
    int* of = p.offs + t*(N+1);
    int base = tid*16;
    int loc[16]; int s = 0;
    #pragma unroll
    for (int i = 0; i < 16; i++){ loc[i] = s; s += dg[base+i]; }
    sm.sh[tid] = s;
    __syncthreads();
    for (int o = 1; o < 256; o <<= 1){
      int v = (tid >= o) ? sm.sh[tid-o] : 0;
      __syncthreads();
      sm.sh[tid] += v;
      __syncthreads();
    }
    int pre = (tid == 0) ? 0 : sm.sh[tid-1];
    #pragma unroll
    for (int i = 0; i < 16; i++){
      int deg_i = dg[base+i];
      of[base+i] = pre + loc[i];
      p.dinv[t*N + base + i] = rsqrtf(1.f + (float)deg_i);
    }
    if (tid == 255) of[N] = sm.sh[255];
    __syncthreads();
    #pragma unroll
    for (int i = 0; i < 16; i++) p.deg[t*N + base + i] = pre + loc[i];  // cursor
  } else if (gb < 36){
    for (int idx = (gb-4)*256 + tid; idx < N*HD; idx += 32*256){
      float v = ldI(p.h0, idx, f);
      p.h_prev[idx] = v; p.h_bf[idx] = f2b(v);
    }
  } else {
    int u = gb - 36;
    int colblk = u & 3, rowblk = u >> 2;
    mfma_tile(sm.g, tid, f, p.x, 1, XD, XD,
              p.phi_x_w, HD, colblk*64, p.phi_x_b, 1,
              p.phiXa, HD, rowblk*64, colblk*64, nullptr, 0, nullptr, 0);
  }
}

// precompute h-independent GEMM halves for ALL steps:
// PreB[t][n][0:256]=phiX@enc_w_top, [256:512]=phiX@gxz_top, [512:768]=phiX@gxr_top, [768:1024]=phiX@gxh_top
__global__ __launch_bounds__(256) void setup3_k(KP p){
  __shared__ GemmSM sm;
  int gb = blockIdx.x, tid = threadIdx.x, f = *p.dflag;
  int colblk = gb & 15, rowblk = gb >> 4;        // rowblk over T*N/64 = 256
  int grp = colblk >> 2, c4 = colblk & 3;
  const void* W;
  if (grp == 0) W = p.enc_w;
  else if (grp == 1) W = p.gxz;
  else if (grp == 2) W = p.gxr;
  else W = p.gxh;
  mfma_tile(sm, tid, f, p.phiXa, 2, HD, 256,
            W, HD, c4*64, nullptr, 0,
            p.PreB, 1024, rowblk*64, colblk*64, nullptr, 0, nullptr, 0);
}

// ---------------- step kernels ----------------
// g1: GEMM tiles (0-1023), all K=256; at t==0, blocks 1024-2047 perform the edge scatter.
__global__ __launch_bounds__(256) void g1_k(KP p, int t){
  __shared__ GemmSM sm;
  int gb = blockIdx.x, tid = threadIdx.x, f = *p.dflag;
  if (gb >= 1024){
    int idx = (gb - 1024)*256 + tid;      // T*E total
    int tt = idx >> 16, e = idx & (E-1);
    int s = p.ei[(size_t)tt*2*E + e] & (N-1);
    int d = p.ei[(size_t)tt*2*E + E + e] & (N-1);
    int pos = atomicAdd(&p.deg[tt*N + d], 1);
    if (pos >= 0 && pos < E){
      p.srcs[(size_t)tt*E + pos] = s;
      p.enorm[(size_t)tt*E + pos] = p.dinv[tt*N + s] * p.dinv[tt*N + d];
    }
    return;
  }
  const bf16* preT = p.PreB + (size_t)t*N*1024;
  int colblk = gb & 15, rowblk = gb >> 4;
  int grp = colblk >> 2, c4 = colblk & 3;
  if (grp == 0)
    mfma_tile(sm, tid, f, p.h_bf, 2, HD, 256,
              wofs(p.enc_w, f, (size_t)256*HD), HD, c4*64, nullptr, 0,
              p.Gs1, 1024, rowblk*64, colblk*64, preT + c4*64, 1024, nullptr, 0);
  else if (grp == 1)
    mfma_tile(sm, tid, f, p.h_bf, 2, HD, 256,
              p.prior_w, HD, c4*64, p.prior_b, 1,
              p.Gs1, 1024, rowblk*64, colblk*64, nullptr, 0, nullptr, 0);
  else if (grp == 2)
    mfma_tile(sm, tid, f, p.h_bf, 2, HD, 256,
              p.ghz, HD, c4*64, nullptr, 0,
              p.Gs1, 1024, rowblk*64, colblk*64, nullptr, 0, nullptr, 0);
  else
    mfma_tile(sm, tid, f, p.h_bf, 2, HD, 256,
              p.ghr, HD, c4*64, nullptr, 0,
              p.Gs1, 1024, rowblk*64, colblk*64, nullptr, 0, nullptr, 0);
}

// fused enc: per 16-node block, aggregate Gs1 cols 0-255 (+enc_b, relu) into LDS,
// then 16x128 K=256 MFMA GEMM -> Gms cols 0-127. blocks 256-383: prior mean/std GEMM.
__global__ __launch_bounds__(256) void encfused_k(KP p, int t){   // grid 384
  __shared__ union { EncSM e; GemmSM g; } sm;
  int gb = blockIdx.x, tid = threadIdx.x, f = *p.dflag;
  if (gb >= 256){
    int u = gb - 256;
    int colblk = u & 1, rowblk = u >> 1;
    mfma_tile(sm.g, tid, f, p.Gs1 + 256, 2, 1024, 256,
              colblk ? p.prior_std_w : p.prior_mean_w, ZD, 0,
              colblk ? p.prior_std_b : p.prior_mean_b, 0,
              p.Gms, 256, rowblk*64, 128 + colblk*64, nullptr, 0, nullptr, 0);
    return;
  }
  const int* offs_t = p.offs + t*(N+1);
  const int* srcs_t = p.srcs + (size_t)t*E;
  const float* en_t = p.enorm + (size_t)t*E;
  const float* dv_t = p.dinv + t*N;
  int g16 = tid >> 4, l = tid & 15;
  int n = gb*16 + g16, c = l*16;
  {
    int e0 = offs_t[n], e1 = offs_t[n+1];
    float d2 = dv_t[n]*dv_t[n];
    float acc[16], va[8], vb[8], vc[8], vd[8];
    ld8b(p.Gs1 + (size_t)n*1024 + c, va);
    ld8b(p.Gs1 + (size_t)n*1024 + c + 8, vb);
    #pragma unroll
    for (int j = 0; j < 8; j++){ acc[j] = d2*va[j]; acc[8+j] = d2*vb[j]; }
    int e = e0;
    for (; e + 1 < e1; e += 2){
      int s0 = srcs_t[e] & (N-1), s1 = srcs_t[e+1] & (N-1);
      float n0 = en_t[e], n1 = en_t[e+1];
      ld8b(p.Gs1 + (size_t)s0*1024 + c, va);
      ld8b(p.Gs1 + (size_t)s0*1024 + c + 8, vb);
      ld8b(p.Gs1 + (size_t)s1*1024 + c, vc);
      ld8b(p.Gs1 + (size_t)s1*1024 + c + 8, vd);
      #pragma unroll
      for (int j = 0; j < 8; j++){ acc[j] += n0*va[j] + n1*vc[j]; acc[8+j] += n0*vb[j] + n1*vd[j]; }
    }
    if (e < e1){
      int s0 = srcs_t[e] & (N-1);
      float n0 = en_t[e];
      ld8b(p.Gs1 + (size_t)s0*1024 + c, va);
      ld8b(p.Gs1 + (size_t)s0*1024 + c + 8, vb);
      #pragma unroll
      for (int j = 0; j < 8; j++){ acc[j] += n0*va[j]; acc[8+j] += n0*vb[j]; }
    }
    #pragma unroll
    for (int j = 0; j < 16; j++) acc[j] = fmaxf(acc[j] + ldI(p.enc_b, c + j, f), 0.f);
    *(uint4*)&sm.e.At[g16*264 + c]     = pack8(acc);
    *(uint4*)&sm.e.At[g16*264 + c + 8] = pack8(acc + 8);
  }
  int wave = tid >> 6, lane = tid & 63, m = lane & 15, kq = lane >> 4;
  int kp2e = (tid >> 4)*2;          // k-pair within 32-chunk (0..30)
  int wn2 = (tid & 15)*8;           // out col 0..120
  f32x4 acc2[2] = {};
  for (int k0 = 0; k0 < 256; k0 += 32){
    const void* Wp = (wn2 < 64) ? p.enc_mean_w : p.enc_std_w;
    int wc = wn2 & 63;
    size_t wi = (size_t)(k0 + kp2e)*ZD + wc;
    short w0[8], w1[8];
    if (f == 0){
      short8 t0 = *(const short8*)((const short*)Wp + wi);
      short8 t1 = *(const short8*)((const short*)Wp + wi + ZD);
      #pragma unroll
      for (int j = 0; j < 8; j++){ w0[j] = t0[j]; w1[j] = t1[j]; }
    } else {
      float wf0[8], wf1[8];
      ldW8(Wp, wi, 1, wf0); ldW8(Wp, wi + ZD, 1, wf1);
      #pragma unroll
      for (int j = 0; j < 8; j++){ w0[j] = f2s(wf0[j]); w1[j] = f2s(wf1[j]); }
    }
    #pragma unroll
    for (int j = 0; j < 8; j++){
      int nrow = wn2 + j;
      int col = (((kp2e >> 3) ^ ((nrow >> 3) & 3)) << 3) | (kp2e & 7);
      *(unsigned int*)&sm.e.Wt[nrow*40 + col] = pack2s(w0[j], w1[j]);
    }
    __syncthreads();
    short8 afr = *(const short8*)&sm.e.At[m*264 + k0 + kq*8];
    #pragma unroll
    for (int t2 = 0; t2 < 2; t2++){
      int nb = wave*32 + t2*16 + m, sb = (nb >> 3) & 3;
      short8 bfr = *(const short8*)&sm.e.Wt[nb*40 + ((kq ^ sb) << 3)];
      acc2[t2] = __builtin_amdgcn_mfma_f32_16x16x32_bf16(afr, bfr, acc2[t2], 0, 0, 0);
    }
    __syncthreads();
  }
  #pragma unroll
  for (int t2 = 0; t2 < 2; t2++){
    int cc = wave*32 + t2*16 + m;
    #pragma unroll
    for (int reg = 0; reg < 4; reg++){
      int node = gb*16 + kq*4 + reg;
      p.Gms[(size_t)node*256 + cc] = f2b(acc2[t2][reg]);
    }
  }
}

// fused: enc mean/std aggregation + reparam + outputs + kld + phi_z GEMM (grid 256)
__global__ __launch_bounds__(256) void msaggpost_k(KP p, int t){
  __shared__ struct { float msh[16*132]; float red[256];
                      short zsh[16*72]; short Wt[256*72]; } sm;   // 48.6 KB
  int gb = blockIdx.x, tid = threadIdx.x, f = *p.dflag;
  // stage phi_z_w [64][256] into Wt[col][k] (transposed + XOR-swizzled), done once
  {
    int wn = (tid & 31)*8, kb = (tid >> 5)*2;
    for (int ko = 0; ko < 64; ko += 16){
      int kk = kb + ko;
      short w0[8], w1[8];
      if (f == 0){
        short8 t0 = *(const short8*)((const short*)p.phi_z_w + (size_t)kk*HD + wn);
        short8 t1 = *(const short8*)((const short*)p.phi_z_w + (size_t)(kk+1)*HD + wn);
        #pragma unroll
        for (int j = 0; j < 8; j++){ w0[j] = t0[j]; w1[j] = t1[j]; }
      } else {
        float a[8], b[8];
        ldW8(p.phi_z_w, (size_t)kk*HD + wn, 1, a);
        ldW8(p.phi_z_w, (size_t)(kk+1)*HD + wn, 1, b);
        #pragma unroll
        for (int j = 0; j < 8; j++){ w0[j] = f2s(a[j]); w1[j] = f2s(b[j]); }
      }
      #pragma unroll
      for (int j = 0; j < 8; j++){
        int nrow = wn + j;
        int pos = (((kk >> 3) ^ ((nrow >> 3) & 7)) << 3) | (kk & 7);
        *(unsigned int*)&sm.Wt[nrow*72 + pos] = pack2s(w0[j], w1[j]);
      }
    }
  }
  const int* offs_t = p.offs + t*(N+1);
  const int* srcs_t = p.srcs + (size_t)t*E;
  const float* en_t = p.enorm + (size_t)t*E;
  const float* dv_t = p.dinv + t*N;
  int g16 = tid >> 4, l = tid & 15;
  int n = gb*16 + g16, c = l*8;
  {
    int e0 = offs_t[n], e1 = offs_t[n+1];
    float d2 = dv_t[n]*dv_t[n];
    float acc[8], va[8], vb[8];
    ld8b(p.Gms + (size_t)n*256 + c, va);
    #pragma unroll
    for (int j = 0; j < 8; j++) acc[j] = d2 * va[j];
    int e = e0;
    for (; e + 1 < e1; e += 2){
      int s0 = srcs_t[e] & (N-1), s1 = srcs_t[e+1] & (N-1);
      float n0 = en_t[e], n1 = en_t[e+1];
      ld8b(p.Gms + (size_t)s0*256 + c, va);
      ld8b(p.Gms + (size_t)s1*256 + c, vb);
      #pragma unroll
      for (int j = 0; j < 8; j++) acc[j] += n0*va[j] + n1*vb[j];
    }
    if (e < e1){
      int s0 = srcs_t[e] & (N-1);
      float n0 = en_t[e];
      ld8b(p.Gms + (size_t)s0*256 + c, va);
      #pragma unroll
      for (int j = 0; j < 8; j++) acc[j] += n0*va[j];
    }
    #pragma unroll
    for (int j = 0; j < 8; j++) sm.msh[g16*132 + c + j] = acc[j];
  }
  __syncthreads();
  float el = 0.f;
  {
    int d0 = l*4;
    float z4[4];
    #pragma unroll
    for (int q = 0; q < 4; q++){
      int d = d0 + q;
      size_t idx = (size_t)n*ZD + d;
      float mean = sm.msh[g16*132 + d] + ldI(p.enc_mean_b, d, f);
      float sd = splus(sm.msh[g16*132 + 64 + d] + ldI(p.enc_std_b, d, f));
      float zv = ldI(p.eps, (size_t)t*N*ZD + idx, f)*sd + mean;
      z4[q] = zv;
      p.zbf[idx] = f2b(zv);
      stO(p.out, OUT_EM + (size_t)t*N*ZD + idx, mean, f);
      float pm = b2f(p.Gms[(size_t)n*256 + 128 + d]);
      float ps = splus(b2f(p.Gms[(size_t)n*256 + 192 + d]));
      stO(p.out, OUT_PM + (size_t)t*N*ZD + idx, pm, f);
      float s1 = sd + 1e-10f, s2 = ps + 1e-10f;
      float dm = mean - pm;
      el += 2.f*(__logf(s2) - __logf(s1)) - (s1*s1 + dm*dm)/(s2*s2) + 1.f;
    }
    *(unsigned int*)&sm.zsh[g16*72 + d0]     = pack2(z4[0], z4[1]);
    *(unsigned int*)&sm.zsh[g16*72 + d0 + 2] = pack2(z4[2], z4[3]);
  }
  sm.red[tid] = el;
  __syncthreads();
  // phi_z GEMM: Tb2[gb*16 .. +15][0:256] = relu(z @ phi_z_w + phi_z_b), K=64 single stage
  {
    int wave = tid >> 6, lane = tid & 63, m = lane & 15, kq = lane >> 4;
    short8 a0 = *(const short8*)&sm.zsh[m*72 + kq*8];
    short8 a1 = *(const short8*)&sm.zsh[m*72 + (kq + 4)*8];
    f32x4 pc[4] = {};
    #pragma unroll
    for (int t4 = 0; t4 < 4; t4++){
      int nb = wave*64 + t4*16 + m, sb = (nb >> 3) & 7;
      short8 b0 = *(const short8*)&sm.Wt[nb*72 + ((kq ^ sb) << 3)];
      short8 b1 = *(const short8*)&sm.Wt[nb*72 + (((kq + 4) ^ sb) << 3)];
      pc[t4] = __builtin_amdgcn_mfma_f32_16x16x32_bf16(a0, b0, pc[t4], 0, 0, 0);
      pc[t4] = __builtin_amdgcn_mfma_f32_16x16x32_bf16(a1, b1, pc[t4], 0, 0, 0);
    }
    #pragma unroll
    for (int t4 = 0; t4 < 4; t4++){
      int col = wave*64 + t4*16 + m;
      float bv = ldI(p.phi_z_b, col, f);
      #pragma unroll
      for (int reg = 0; reg < 4; reg++){
        int node = gb*16 + kq*4 + reg;
        p.Tb2[(size_t)node*HD + col] = f2b(fmaxf(pc[t4][reg] + bv, 0.f));
      }
    }
  }
  // kld reduce (red written before the barrier above)
  for (int o = 128; o > 0; o >>= 1){ if (tid < o) sm.red[tid] += sm.red[tid+o]; __syncthreads(); }
  if (tid == 0) atomicAdd(p.scal + 4, sm.red[0] * (0.5f/((float)N*(float)ZD)));
}

// gru-x GEMM (0-767, K=256, phiX half from PreB, h-side gate halves pre-added from Gs1)
// + dec tiles 0-1023 (768-1791)
__global__ __launch_bounds__(256) void grux_dec_k(KP p, int t){   // grid 1792
  __shared__ union { GemmSM g; DecSM z; } sm;
  int gb = blockIdx.x, tid = threadIdx.x, f = *p.dflag;
  if (gb < 768){
    int colblk = gb % 12, rowblk = gb / 12;
    int grp = colblk >> 2, c4 = colblk & 3;
    const void* W = (grp == 0) ? p.gxz : ((grp == 1) ? p.gxr : p.gxh);
    const bf16* pre2 = (grp == 0) ? (p.Gs1 + 512 + c4*64)
                     : (grp == 1) ? (p.Gs1 + 768 + c4*64) : nullptr;
    mfma_tile(sm.g, tid, f, p.Tb2, 2, HD, 256,
              wofs(W, f, (size_t)256*HD), HD, c4*64, nullptr, 0,
              p.Gsx, 768, rowblk*64, colblk*64,
              p.PreB + (size_t)t*N*1024 + 256 + colblk*64, 1024,
              pre2, 1024);
  } else {
    dec_tile1(p, sm.z, tid, t, gb - 768, f);
  }
}

// z/r gates (0-1023) + dec tiles 1024-2047 (1024-2047)
__global__ __launch_bounds__(256) void zr_k(KP p, int t){   // grid 2048
  __shared__ DecSM smz;
  int gb = blockIdx.x, tid = threadIdx.x;
  if (gb >= 1024){
    dec_tile1(p, smz, tid, t, gb, *p.dflag);   // u = 1024 + (gb-1024) = gb
    return;
  }
  const int* offs_t = p.offs + t*(N+1);
  const int* srcs_t = p.srcs + (size_t)t*E;
  const float* en_t = p.enorm + (size_t)t*E;
  const float* dv_t = p.dinv + t*N;
  int g4 = tid >> 6, lane = tid & 63;
  int n = gb*4 + g4, c = lane*8;
  int e0 = offs_t[n], e1 = offs_t[n+1];
  float d2 = dv_t[n]*dv_t[n];
  float acc[8], v1[8], v2[8];
  ld8b(p.Gsx + (size_t)n*768 + c, v1);
  #pragma unroll
  for (int j = 0; j < 8; j++) acc[j] = d2 * v1[j];
  int e = e0;
  for (; e + 1 < e1; e += 2){
    int s0 = srcs_t[e] & (N-1), s1 = srcs_t[e+1] & (N-1);
    float n0 = en_t[e], n1 = en_t[e+1];
    ld8b(p.Gsx + (size_t)s0*768 + c, v1);
    ld8b(p.Gsx + (size_t)s1*768 + c, v2);
    #pragma unroll
    for (int j = 0; j < 8; j++) acc[j] += n0*v1[j] + n1*v2[j];
  }
  if (e < e1){
    int s0 = srcs_t[e] & (N-1);
    float n0 = en_t[e];
    ld8b(p.Gsx + (size_t)s0*768 + c, v1);
    #pragma unroll
    for (int j = 0; j < 8; j++) acc[j] += n0*v1[j];
  }
  if (c < 256){
    size_t base = (size_t)n*HD + c;
    float4 o0, o1;
    o0.x = sigm(acc[0]); o0.y = sigm(acc[1]); o0.z = sigm(acc[2]); o0.w = sigm(acc[3]);
    o1.x = sigm(acc[4]); o1.y = sigm(acc[5]); o1.z = sigm(acc[6]); o1.w = sigm(acc[7]);
    *(float4*)(p.z_g + base) = o0;
    *(float4*)(p.z_g + base + 4) = o1;
  } else {
    size_t base = (size_t)n*HD + (c - 256);
    float r[8];
    #pragma unroll
    for (int j = 0; j < 8; j++) r[j] = sigm(acc[j]) * p.h_prev[base+j];
    *(uint4*)(p.Tb1 + base) = pack8(r);
  }
}

// (r*h)@ghh GEMM (0-255) + dec tiles 2048-3071 (256-1279)
__global__ __launch_bounds__(256) void hh_k(KP p, int t){   // grid 1280
  __shared__ union { GemmSM g; DecSM z; } sm;
  int gb = blockIdx.x, tid = threadIdx.x, f = *p.dflag;
  if (gb >= 256){
    dec_tile1(p, sm.z, tid, t, 2048 + (gb - 256), f);
    return;
  }
  int colblk = gb & 3, rowblk = gb >> 2;
  mfma_tile(sm.g, tid, f, p.Tb1, 2, HD, 256,
            p.ghh, HD, colblk*64, nullptr, 0,
            p.Gh2, 256, rowblk*64, colblk*64, nullptr, 0,
            p.Gsx + 512 + colblk*64, 768);
}

// h update (0-511) + dec tiles 3072-4095 (512-1535)
__global__ __launch_bounds__(256) void hagg_k(KP p, int t){   // grid 1536
  __shared__ DecSM smz;
  int gb = blockIdx.x, tid = threadIdx.x, f = *p.dflag;
  if (gb >= 512){
    dec_tile1(p, smz, tid, t, 3072 + (gb - 512), f);
    return;
  }
  const int* offs_t = p.offs + t*(N+1);
  const int* srcs_t = p.srcs + (size_t)t*E;
  const float* en_t = p.enorm + (size_t)t*E;
  const float* dv_t = p.dinv + t*N;
  int g8 = tid >> 5, l = tid & 31;
  int n = gb*8 + g8, c = l*8;
  int e0 = offs_t[n], e1 = offs_t[n+1];
  float d2 = dv_t[n]*dv_t[n];
  float acc[8], v1[8], v2[8];
  ld8b(p.Gh2 + (size_t)n*256 + c, v1);
  #pragma unroll
  for (int j = 0; j < 8; j++) acc[j] = d2 * v1[j];
  int e = e0;
  for (; e + 1 < e1; e += 2){
    int s0 = srcs_t[e] & (N-1), s1 = srcs_t[e+1] & (N-1);
    float n0 = en_t[e], n1 = en_t[e+1];
    ld8b(p.Gh2 + (size_t)s0*256 + c, v1);
    ld8b(p.Gh2 + (size_t)s1*256 + c, v2);
    #pragma unroll
    for (int j = 0; j < 8; j++) acc[j] += n0*v1[j] + n1*v2[j];
  }
  if (e < e1){
    int s0 = srcs_t[e] & (N-1);
    float n0 = en_t[e];
    ld8b(p.Gh2 + (size_t)s0*256 + c, v1);
    #pragma unroll
    for (int j = 0; j < 8; j++) acc[j] += n0*v1[j];
  }
  size_t base = (size_t)n*HD + c;
  #pragma unroll
  for (int j = 0; j < 8; j++){
    float z = p.z_g[base+j];
    float hv = p.h_prev[base+j];
    float nv = z*hv + (1.f - z)*ftanh(acc[j]);
    p.h_prev[base+j] = nv;
    p.h_bf[base+j] = f2b(nv);
    if (t == T_STEPS-1) stO(p.out, OUT_H + base + j, nv, f);
  }
}

// finalize kld/nll (own dispatch: hagg's dec tiles must finish updating scal first)
__global__ __launch_bounds__(64) void fin_k(KP p){
  if (threadIdx.x == 0){
    int f = *p.dflag;
    const float NNf = 16777216.f;
    float nll = 0.f;
    for (int tt = 0; tt < T_STEPS; tt++){
      float ts = p.scal[8+tt], P = p.scal[12+tt], Q = p.scal[16+tt];
      float posw = (NNf - ts)/ts;
      nll += (posw*P + Q) * 0.5f/(NNf - ts);
    }
    stO(p.out, 0, p.scal[4], f);
    stO(p.out, 1, nll, f);
  }
}

// ---------------- host ----------------
extern "C" void kernel_launch(void* const* d_in, const int* in_sizes, int n_in,
                              void* d_out, int out_size, void* d_ws, size_t ws_size,
                              hipStream_t stream){
  KP P;
  P.x = d_in[0];  P.ei = (const int*)d_in[1];  P.adj = d_in[2];  P.eps = d_in[3];  P.h0 = d_in[4];
  P.phi_x_w = d_in[5];  P.phi_x_b = d_in[6];  P.phi_z_w = d_in[7];  P.phi_z_b = d_in[8];
  P.enc_w = d_in[9];  P.enc_b = d_in[10];
  P.enc_mean_w = d_in[11];  P.enc_mean_b = d_in[12];
  P.enc_std_w = d_in[13];   P.enc_std_b = d_in[14];
  P.prior_w = d_in[15];  P.prior_b = d_in[16];
  P.prior_mean_w = d_in[17];  P.prior_mean_b = d_in[18];
  P.prior_std_w = d_in[19];   P.prior_std_b = d_in[20];
  P.gxz = d_in[21];  P.ghz = d_in[22];  P.gxr = d_in[23];
  P.ghr = d_in[24];  P.gxh = d_in[25];  P.ghh = d_in[26];
  P.out = d_out;

  char* wp = (char*)d_ws;
  auto alloc = [&](size_t bytes){ void* q = (void*)wp; wp += (bytes + 255) & ~(size_t)255; return q; };
  P.scal  = (float*)alloc(64*sizeof(float));
  P.dflag = (int*)  alloc(256);
  P.dinv  = (float*)alloc((size_t)T_STEPS*N*4);
  P.offs  = (int*)  alloc((size_t)T_STEPS*(N+1)*4);
  P.srcs  = (int*)  alloc((size_t)T_STEPS*E*4);
  P.enorm = (float*)alloc((size_t)T_STEPS*E*4);
  P.deg   = (int*)  alloc((size_t)T_STEPS*N*4);
  P.h_prev= (float*)alloc((size_t)N*HD*4);
  P.h_bf  = (bf16*) alloc((size_t)N*HD*2);
  P.phiXa = (bf16*) alloc((size_t)T_STEPS*N*HD*2);
  P.Tb1   = (bf16*) alloc((size_t)N*HD*2);
  P.Tb2   = (bf16*) alloc((size_t)N*HD*2);
  P.zbf   = (bf16*) alloc((size_t)N*ZD*2);
  P.z_g   = (float*)alloc((size_t)N*HD*4);
  P.Gs1   = (bf16*) alloc((size_t)N*1024*2);
  P.Gsx   = (bf16*) alloc((size_t)N*768*2);
  P.Gms   = (bf16*) alloc((size_t)N*256*2);
  P.Gh2   = (bf16*) alloc((size_t)N*256*2);
  P.PreB  = (bf16*) alloc((size_t)T_STEPS*N*1024*2);

  setup0_k<<<66,256,0,stream>>>(P);
  count_deg_k<<<1024,256,0,stream>>>(P);
  setup2_k<<<1060,256,0,stream>>>(P);
  setup3_k<<<4096,256,0,stream>>>(P);
  for (int t = 0; t < T_STEPS; t++){
    g1_k<<<(t == 0) ? 2048 : 1024,256,0,stream>>>(P, t);   // t=0 carries edge scatter
    encfused_k<<<384,256,0,stream>>>(P, t);
    msaggpost_k<<<256,256,0,stream>>>(P, t);               // + fused phi_z GEMM
    grux_dec_k<<<1792,256,0,stream>>>(P, t);               // GEMMs + dec 0-1023
    zr_k<<<2048,256,0,stream>>>(P, t);                     // gates + dec 1024-2047
    hh_k<<<1280,256,0,stream>>>(P, t);                     // GEMM + dec 2048-3071
    hagg_k<<<1536,256,0,stream>>>(P, t);                   // h update + dec 3072-4095
  }
  fin_k<<<1,64,0,stream>>>(P);
}